// Round 16
// baseline (129.635 us; speedup 1.0000x reference)
//
#include <hip/hip_runtime.h>
#include <stdint.h>

// Problem constants (B=1, L=256, C=128, N=4, TN=4)
#define LLTOT 65536
#define CDIM  128
#define WPB   4                         // waves per block
#define NBLK  (LLTOT / (WPB * 16))      // 1024 blocks, 16 pixels per wave

typedef float f32x4 __attribute__((ext_vector_type(4)));
typedef short s16x8 __attribute__((ext_vector_type(8)));

#define MFMA16(a, b, c) __builtin_amdgcn_mfma_f32_16x16x32_bf16((a), (b), (c), 0, 0, 0)

// ---- persistent device scratch (weights only) ----
// g_wefff: routing weights, 16x16 A-frag tiles [tile2][kk4][lane][8]
// g_w1gf : W1*ln_g,        [T tile 0..31][kk4][lane][8]   j=T*16+(l&15), c=kk*32+(l>>4)*8+e
// g_w2f16: W2,             [ksg 0..15][ct 0..7][lane][8]  c=ct*16+(l&15), k=ksg*32+(l>>4)*8+e
__device__ __align__(16) unsigned short g_wefff[2 * 4 * 64 * 8];
__device__ __align__(16) unsigned short g_w1gf[32 * 4 * 64 * 8];
__device__ __align__(16) unsigned short g_w2f16[16 * 8 * 64 * 8];
__device__ __align__(16) float  g_hA[512];
__device__ __align__(16) float  g_w1gs[512];

__device__ __forceinline__ unsigned short f2bf(float f) {
    union { float f; uint32_t u; } v; v.f = f;
    uint32_t u = v.u;
    return (unsigned short)((u + 0x7FFFu + ((u >> 16) & 1u)) >> 16);
}
__device__ __forceinline__ uint32_t pack2(float a, float b) {
    uint32_t r;
    asm("v_cvt_pk_bf16_f32 %0, %1, %2" : "=v"(r) : "v"(a), "v"(b));
    return r;
}
__device__ __forceinline__ float bf2f(uint32_t lo16) { return __uint_as_float(lo16 << 16); }

__device__ __forceinline__ float fast_tanh(float x) {
    float cx = fminf(fmaxf(x, -10.f), 10.f);
    float e = __expf(2.f * cx);
    return (e - 1.f) * __builtin_amdgcn_rcpf(e + 1.f);
}
__device__ __forceinline__ float fast_sig(float z) {
    return __builtin_amdgcn_rcpf(1.f + __expf(-z));
}

// ---- prep ----
__global__ void prep_kernel(const float* __restrict__ Wpre, const float* __restrict__ Wpost,
                            const float* __restrict__ Wres, const float* __restrict__ W1,
                            const float* __restrict__ W2, const float* __restrict__ ln_g,
                            const float* __restrict__ ln_b, const float* __restrict__ b1) {
    int b = blockIdx.x, t = threadIdx.x;
    if (b == 264) {
        int j = t;
        float sg = 0.f, sb = 0.f;
        const float* row = W1 + j * 128;
        #pragma unroll 4
        for (int c = 0; c < 128; c += 4) {
            float4 wv = *(const float4*)(row + c);
            float4 gv = *(const float4*)(ln_g + c);
            float4 bv = *(const float4*)(ln_b + c);
            sg += wv.x*gv.x + wv.y*gv.y + wv.z*gv.z + wv.w*gv.w;
            sb += wv.x*bv.x + wv.y*bv.y + wv.z*bv.z + wv.w*bv.w;
        }
        g_hA[j]   = b1[j] + sb;
        g_w1gs[j] = sg;
        return;
    }
    int idx = b * 512 + t;
    if (idx < 4096) {
        int e = idx & 7, lane = (idx >> 3) & 63, kk = (idx >> 9) & 3, tile = idx >> 11;
        int o = tile * 16 + (lane & 15);
        int c = kk * 32 + (lane >> 4) * 8 + e;
        float v = 0.f;
        if (o < 4)        v = Wpre[o*512+c] + Wpre[o*512+128+c] + Wpre[o*512+256+c] + Wpre[o*512+384+c];
        else if (o < 8)   { int j = o - 4;  v = Wpost[j*512+c] + Wpost[j*512+128+c] + Wpost[j*512+256+c] + Wpost[j*512+384+c]; }
        else if (o < 24)  { int j = o - 8;  v = Wres[j*512+c] + Wres[j*512+128+c] + Wres[j*512+256+c] + Wres[j*512+384+c]; }
        g_wefff[idx] = f2bf(v);
    } else if (idx < 69632) {
        int d = idx - 4096;
        int e = d & 7, lane = (d >> 3) & 63, kk = (d >> 9) & 3, jt = d >> 11;
        int j = jt * 16 + (lane & 15);
        int c = kk * 32 + (lane >> 4) * 8 + e;
        g_w1gf[d] = f2bf(W1[j * 128 + c] * ln_g[c]);
    } else if (idx < 135168) {
        int d = idx - 69632;   // 16x16 A-frag layout for W2: [ksg][ct][lane][8]
        int e = d & 7, lane = (d >> 3) & 63, ct = (d >> 9) & 7, ksg = d >> 12;
        int c = ct * 16 + (lane & 15);
        int k = ksg * 32 + (lane >> 4) * 8 + e;
        g_w2f16[d] = f2bf(W2[c * 512 + k]);
    }
}

// ---- fused: ZERO barriers; each wave owns 16 pixels end-to-end ----
__global__ void fused_kernel(
    const float* __restrict__ p, const float* __restrict__ p_mask,
    const float* __restrict__ b_pre, const float* __restrict__ b_post, const float* __restrict__ b_res,
    const float* __restrict__ a_pre, const float* __restrict__ a_post, const float* __restrict__ a_res,
    const float* __restrict__ b2g, float* __restrict__ out)
{
    __shared__ __align__(16) unsigned short pf_lds[WPB][4 * 512];      // 4 KB/wave: p frags [kk][lane][8]
    __shared__ __align__(16) unsigned short h_lds[WPB][2][4 * 512];    // 2 x 4 KB/wave: h chunk, B-frag-linear

    const int t = threadIdx.x;
    const int w = t >> 6, l = t & 63, lr = l & 15, lk = l >> 4;
    const size_t gbase = ((size_t)blockIdx.x * WPB + w) * 16;   // first pixel of this wave

    unsigned short* pfb = pf_lds[w];

    // ======== route + Sinkhorn (per-wave, r6-proven form; outputs stay in registers) ========
    float Aval, Bval, si, mi;
    s16x8 pf[4];
    {
        const int g = lk, pixl = lr;
        const size_t gpix = gbase + pixl;
        float apre = a_pre[0], apost = a_post[0], ares = a_res[0];
        float msk = p_mask[gpix];
        float bp0 = b_pre[0], bp1 = b_pre[1], bp2 = b_pre[2], bp3 = b_pre[3];
        float bq0 = b_post[0], bq1 = b_post[1], bq2 = b_post[2], bq3 = b_post[3];
        int mrow = (g + 2) & 3;
        float br0 = b_res[mrow*4+0], br1 = b_res[mrow*4+1], br2 = b_res[mrow*4+2], br3 = b_res[mrow*4+3];

        float s = 0.f, ss = 0.f;
        const float* prow = p + gpix * 128 + g * 8;
        #pragma unroll
        for (int kk = 0; kk < 4; ++kk) {
            float4 va = *(const float4*)(prow + kk * 32);
            float4 vb = *(const float4*)(prow + kk * 32 + 4);
            s  += va.x + va.y + va.z + va.w + vb.x + vb.y + vb.z + vb.w;
            ss += va.x*va.x + va.y*va.y + va.z*va.z + va.w*va.w
                + vb.x*vb.x + vb.y*vb.y + vb.z*vb.z + vb.w*vb.w;
            union { s16x8 v; uint32_t u[4]; } cc;
            cc.u[0] = pack2(va.x, va.y);
            cc.u[1] = pack2(va.z, va.w);
            cc.u[2] = pack2(vb.x, vb.y);
            cc.u[3] = pack2(vb.z, vb.w);
            pf[kk] = cc.v;
            *(s16x8*)(pfb + kk * 512 + l * 8) = cc.v;
        }
        s  += __shfl_xor(s, 16);  ss += __shfl_xor(ss, 16);
        s  += __shfl_xor(s, 32);  ss += __shfl_xor(ss, 32);
        float mu = s * (1.f / 128.f), mq = ss * (1.f / 128.f);
        float rv  = rsqrtf(mq + 1.1920929e-07f);
        float var = mq - mu * mu;

        f32x4 y1 = {0.f, 0.f, 0.f, 0.f}, y2 = {0.f, 0.f, 0.f, 0.f};
        #pragma unroll
        for (int kk = 0; kk < 4; ++kk) {
            s16x8 a0 = *(const s16x8*)(g_wefff + ((size_t)(kk) * 64 + l) * 8);
            s16x8 a1 = *(const s16x8*)(g_wefff + ((size_t)(4 + kk) * 64 + l) * 8);
            y1 = MFMA16(a0, pf[kk], y1);
            y2 = MFMA16(a1, pf[kk], y2);
        }
        #pragma unroll
        for (int r = 0; r < 4; ++r) { y1[r] *= rv; y2[r] *= rv; }

        float sp_loc = fast_sig(apre * fast_tanh(y1[0]) + bp0)
                     + fast_sig(apre * fast_tanh(y1[1]) + bp1)
                     + fast_sig(apre * fast_tanh(y1[2]) + bp2)
                     + fast_sig(apre * fast_tanh(y1[3]) + bp3);
        float sp = __shfl(sp_loc, pixl);

        float hp0 = 2.f * fast_sig(apost * fast_tanh(y1[0]) + bq0);
        float hp1 = 2.f * fast_sig(apost * fast_tanh(y1[1]) + bq1);
        float hp2 = 2.f * fast_sig(apost * fast_tanh(y1[2]) + bq2);
        float hp3 = 2.f * fast_sig(apost * fast_tanh(y1[3]) + bq3);

        bool lo = g < 2;
        float M0 = __expf(ares * fast_tanh(lo ? y2[0] : y1[0]) + br0);
        float M1 = __expf(ares * fast_tanh(lo ? y2[1] : y1[1]) + br1);
        float M2 = __expf(ares * fast_tanh(lo ? y2[2] : y1[2]) + br2);
        float M3 = __expf(ares * fast_tanh(lo ? y2[3] : y1[3]) + br3);
        #pragma unroll 1
        for (int it = 0; it < 20; ++it) {
            float ri = __builtin_amdgcn_rcpf(M0 + M1 + M2 + M3);
            M0 *= ri; M1 *= ri; M2 *= ri; M3 *= ri;
            float c0 = M0, c1 = M1, c2 = M2, c3 = M3;
            c0 += __shfl_xor(c0, 16); c1 += __shfl_xor(c1, 16); c2 += __shfl_xor(c2, 16); c3 += __shfl_xor(c3, 16);
            c0 += __shfl_xor(c0, 32); c1 += __shfl_xor(c1, 32); c2 += __shfl_xor(c2, 32); c3 += __shfl_xor(c3, 32);
            M0 *= __builtin_amdgcn_rcpf(c0); M1 *= __builtin_amdgcn_rcpf(c1);
            M2 *= __builtin_amdgcn_rcpf(c2); M3 *= __builtin_amdgcn_rcpf(c3);
        }
        float rm = M0 + M1 + M2 + M3;

        float h0b = __shfl(hp0, pixl + 16);
        float h1b = __shfl(hp1, pixl + 16);
        float h2b = __shfl(hp2, pixl + 16);
        float h3b = __shfl(hp3, pixl + 16);
        float hpm = (mrow & 2) ? ((mrow & 1) ? h3b : h2b) : ((mrow & 1) ? h1b : h0b);

        Aval = rm + hpm * sp;        // A[pixl][mrow] held at lane (g, pixl)
        Bval = hpm * msk;
        float istd = rsqrtf(sp * sp * var + 1e-5f);
        si = sp * istd;              // valid for pixel lr on every lane
        mi = sp * mu * istd;
    }

    // ======== 4 K-chunks: GEMM1(128 j) -> fold -> h chunk (wave-private LDS) -> GEMM2 partial ========
    f32x4 acc2[8] = {};   // c-tile ct = 0..7 (c = ct*16 + lk*4 + r ; pix = lr)
    #pragma unroll 1
    for (int chunk = 0; chunk < 4; ++chunk) {
        unsigned short* hb = h_lds[w][chunk & 1];

        // GEMM1: 8 j-tiles x 4 kk
        f32x4 acc1[8] = {};
        #pragma unroll
        for (int kk = 0; kk < 4; ++kk)
            #pragma unroll
            for (int jt = 0; jt < 8; ++jt) {
                s16x8 a = *(const s16x8*)(g_w1gf + ((size_t)((chunk * 8 + jt) * 4 + kk) * 64 + l) * 8);
                acc1[jt] = MFMA16(a, pf[kk], acc1[jt]);
            }

        // fold + write h chunk in 16x16 B-frag-linear layout (wave-private, no barrier)
        #pragma unroll
        for (int jt = 0; jt < 8; ++jt) {
            int j0 = chunk * 128 + jt * 16 + lk * 4;
            float4 wg = *(const float4*)(g_w1gs + j0);
            float4 ha = *(const float4*)(g_hA + j0);
            f32x4 v = acc1[jt];
            float h0 = fmaxf(fmaf(si, v[0], fmaf(-mi, wg.x, ha.x)), 0.f);
            float h1 = fmaxf(fmaf(si, v[1], fmaf(-mi, wg.y, ha.y)), 0.f);
            float h2 = fmaxf(fmaf(si, v[2], fmaf(-mi, wg.z, ha.z)), 0.f);
            float h3 = fmaxf(fmaf(si, v[3], fmaf(-mi, wg.w, ha.w)), 0.f);
            uint2 uu;
            uu.x = pack2(h0, h1);
            uu.y = pack2(h2, h3);
            // j_in_chunk = jt*16 + lk*4 + r : ks = jt>>1 ; laneB = lr + 16*((jt&1)*2 + (lk>>1)) ; e0 = (lk&1)*4
            int addr_sh = (jt >> 1) * 512 + (lr + 16 * ((jt & 1) * 2 + (lk >> 1))) * 8 + (lk & 1) * 4;
            *(uint2*)(hb + addr_sh) = uu;
        }

        // drain LDS writes so cross-lane reads below see them (same wave, no s_barrier needed)
        asm volatile("s_waitcnt lgkmcnt(0)" ::: "memory");
        __builtin_amdgcn_sched_barrier(0);

        // GEMM2 partial: 4 k-steps x 8 c-tiles
        #pragma unroll
        for (int ks = 0; ks < 4; ++ks) {
            s16x8 b = *(const s16x8*)(hb + ks * 512 + l * 8);
            #pragma unroll
            for (int ct = 0; ct < 8; ++ct) {
                s16x8 a = *(const s16x8*)(g_w2f16 + ((size_t)((chunk * 4 + ks) * 8 + ct) * 64 + l) * 8);
                acc2[ct] = MFMA16(a, b, acc2[ct]);
            }
        }
    }

    // ======== epilogue: out[pix][m][c] = A*p + B*(D + b2), straight from acc2 ========
    float Am[4], Bm[4];
    #pragma unroll
    for (int m = 0; m < 4; ++m) {
        int src = lr + 16 * ((m + 2) & 3);
        Am[m] = __shfl(Aval, src);
        Bm[m] = __shfl(Bval, src);
    }
    float* og0 = out + (gbase + lr) * 512 + lk * 4;
    #pragma unroll
    for (int ct = 0; ct < 8; ++ct) {
        float4 b2v = *(const float4*)(b2g + ct * 16 + lk * 4);
        // p[pix=lr][c=ct*16+lk*4 .. +3] from wave-private pf LDS
        const unsigned short* pe = pfb + (ct >> 1) * 512
            + (lr + 16 * ((2 * ct + (lk >> 1)) & 3)) * 8 + (lk & 1) * 4;
        uint2 pb = *(const uint2*)pe;
        float p0 = bf2f(pb.x & 0xffffu), p1 = __uint_as_float(pb.x & 0xffff0000u);
        float p2 = bf2f(pb.y & 0xffffu), p3 = __uint_as_float(pb.y & 0xffff0000u);
        float d0 = acc2[ct][0] + b2v.x;
        float d1 = acc2[ct][1] + b2v.y;
        float d2 = acc2[ct][2] + b2v.z;
        float d3 = acc2[ct][3] + b2v.w;
        float* og = og0 + ct * 16;
        #pragma unroll
        for (int m = 0; m < 4; ++m) {
            f32x4 o;
            o[0] = Am[m] * p0 + Bm[m] * d0;
            o[1] = Am[m] * p1 + Bm[m] * d1;
            o[2] = Am[m] * p2 + Bm[m] * d2;
            o[3] = Am[m] * p3 + Bm[m] * d3;
            *(f32x4*)(og + m * 128) = o;
        }
    }
}

extern "C" void kernel_launch(void* const* d_in, const int* in_sizes, int n_in,
                              void* d_out, int out_size, void* d_ws, size_t ws_size,
                              hipStream_t stream) {
    const float* p      = (const float*)d_in[0];
    const float* p_mask = (const float*)d_in[1];
    const float* W_pre  = (const float*)d_in[2];
    const float* W_post = (const float*)d_in[3];
    const float* W_res  = (const float*)d_in[4];
    const float* b_pre  = (const float*)d_in[5];
    const float* b_post = (const float*)d_in[6];
    const float* b_res  = (const float*)d_in[7];
    const float* a_pre  = (const float*)d_in[8];
    const float* a_post = (const float*)d_in[9];
    const float* a_res  = (const float*)d_in[10];
    const float* ln_g   = (const float*)d_in[11];
    const float* ln_b   = (const float*)d_in[12];
    const float* W1     = (const float*)d_in[13];
    const float* b1     = (const float*)d_in[14];
    const float* W2     = (const float*)d_in[15];
    const float* b2     = (const float*)d_in[16];
    float* out = (float*)d_out;

    prep_kernel<<<265, 512, 0, stream>>>(W_pre, W_post, W_res, W1, W2, ln_g, ln_b, b1);
    fused_kernel<<<NBLK, WPB * 64, 0, stream>>>(p, p_mask, b_pre, b_post, b_res,
                                                a_pre, a_post, a_res, b2, out);
}

// Round 17
// 97.692 us; speedup vs baseline: 1.3270x; 1.3270x over previous
//
#include <hip/hip_runtime.h>
#include <stdint.h>

// Problem constants (B=1, L=256, C=128, N=4, TN=4)
#define LLTOT 65536
#define CDIM  128
#define TILES 4
#define NBLK  (LLTOT / (TILES * 32))   // 512 blocks, 640 threads (10 waves)

typedef float f32x4 __attribute__((ext_vector_type(4)));
typedef short s16x8 __attribute__((ext_vector_type(8)));

#define MFMA16(a, b, c) __builtin_amdgcn_mfma_f32_16x16x32_bf16((a), (b), (c), 0, 0, 0)

// lgkm-only barrier: LDS coherence without draining global stores
#define SYNCB() do {                                        \
    __builtin_amdgcn_sched_barrier(0);                      \
    asm volatile("s_waitcnt lgkmcnt(0)" ::: "memory");      \
    __builtin_amdgcn_s_barrier();                           \
    __builtin_amdgcn_sched_barrier(0);                      \
} while (0)

// ---- persistent device scratch (weights only) ----
// g_wefff: routing weights 16x16 A-frags [tile2][kk4][lane][8]
// g_w1gf : W1*ln_g A-frags [T 0..31][kk4][lane][8]   j=T*16+(l&15), c=kk*32+(l>>4)*8+e
// g_w2f16: W2 A-frags      [ksg 0..15][ct 0..7][lane][8]  c=ct*16+(l&15), k=ksg*32+(l>>4)*8+e
__device__ __align__(16) unsigned short g_wefff[2 * 4 * 64 * 8];
__device__ __align__(16) unsigned short g_w1gf[32 * 4 * 64 * 8];
__device__ __align__(16) unsigned short g_w2f16[16 * 8 * 64 * 8];
__device__ __align__(16) float  g_hA[512];
__device__ __align__(16) float  g_w1gs[512];

__device__ __forceinline__ unsigned short f2bf(float f) {
    union { float f; uint32_t u; } v; v.f = f;
    uint32_t u = v.u;
    return (unsigned short)((u + 0x7FFFu + ((u >> 16) & 1u)) >> 16);
}
__device__ __forceinline__ uint32_t pack2(float a, float b) {
    uint32_t r;
    asm("v_cvt_pk_bf16_f32 %0, %1, %2" : "=v"(r) : "v"(a), "v"(b));
    return r;
}
__device__ __forceinline__ float bf2f(uint32_t lo16) { return __uint_as_float(lo16 << 16); }

__device__ __forceinline__ float fast_tanh(float x) {
    float cx = fminf(fmaxf(x, -10.f), 10.f);
    float e = __expf(2.f * cx);
    return (e - 1.f) * __builtin_amdgcn_rcpf(e + 1.f);
}
__device__ __forceinline__ float fast_sig(float z) {
    return __builtin_amdgcn_rcpf(1.f + __expf(-z));
}

// ---- prep (r16 layouts) ----
__global__ void prep_kernel(const float* __restrict__ Wpre, const float* __restrict__ Wpost,
                            const float* __restrict__ Wres, const float* __restrict__ W1,
                            const float* __restrict__ W2, const float* __restrict__ ln_g,
                            const float* __restrict__ ln_b, const float* __restrict__ b1) {
    int b = blockIdx.x, t = threadIdx.x;
    if (b == 264) {
        int j = t;
        float sg = 0.f, sb = 0.f;
        const float* row = W1 + j * 128;
        #pragma unroll 4
        for (int c = 0; c < 128; c += 4) {
            float4 wv = *(const float4*)(row + c);
            float4 gv = *(const float4*)(ln_g + c);
            float4 bv = *(const float4*)(ln_b + c);
            sg += wv.x*gv.x + wv.y*gv.y + wv.z*gv.z + wv.w*gv.w;
            sb += wv.x*bv.x + wv.y*bv.y + wv.z*bv.z + wv.w*bv.w;
        }
        g_hA[j]   = b1[j] + sb;
        g_w1gs[j] = sg;
        return;
    }
    int idx = b * 512 + t;
    if (idx < 4096) {
        int e = idx & 7, lane = (idx >> 3) & 63, kk = (idx >> 9) & 3, tile = idx >> 11;
        int o = tile * 16 + (lane & 15);
        int c = kk * 32 + (lane >> 4) * 8 + e;
        float v = 0.f;
        if (o < 4)        v = Wpre[o*512+c] + Wpre[o*512+128+c] + Wpre[o*512+256+c] + Wpre[o*512+384+c];
        else if (o < 8)   { int j = o - 4;  v = Wpost[j*512+c] + Wpost[j*512+128+c] + Wpost[j*512+256+c] + Wpost[j*512+384+c]; }
        else if (o < 24)  { int j = o - 8;  v = Wres[j*512+c] + Wres[j*512+128+c] + Wres[j*512+256+c] + Wres[j*512+384+c]; }
        g_wefff[idx] = f2bf(v);
    } else if (idx < 69632) {
        int d = idx - 4096;
        int e = d & 7, lane = (d >> 3) & 63, kk = (d >> 9) & 3, jt = d >> 11;
        int j = jt * 16 + (lane & 15);
        int c = kk * 32 + (lane >> 4) * 8 + e;
        g_w1gf[d] = f2bf(W1[j * 128 + c] * ln_g[c]);
    } else if (idx < 135168) {
        int d = idx - 69632;   // [ksg][ct][lane][8]
        int e = d & 7, lane = (d >> 3) & 63, ct = (d >> 9) & 7, ksg = d >> 12;
        int c = ct * 16 + (lane & 15);
        int k = ksg * 32 + (lane >> 4) * 8 + e;
        g_w2f16[d] = f2bf(W2[c * 512 + k]);
    }
}

// ---- fused: 10 waves; waves 0-1 route(t+1) while waves 2-9 MLP(t); 2 lgkm-barriers/tile ----
__global__ void fused_kernel(
    const float* __restrict__ p, const float* __restrict__ p_mask,
    const float* __restrict__ b_pre, const float* __restrict__ b_post, const float* __restrict__ b_res,
    const float* __restrict__ a_pre, const float* __restrict__ a_post, const float* __restrict__ a_res,
    const float* __restrict__ b2g, float* __restrict__ out)
{
    __shared__ __align__(16) unsigned short pf_lds[2][8 * 512];   // 16 KB: p frags, dbuf
    __shared__ __align__(16) unsigned short h16[32 * 512];        // 32 KB: h B-frags [ksg*2+it][lane][8]
    __shared__ __align__(16) float A_s[2][128], B_s[2][128];      // 2 KB
    __shared__ __align__(16) float2 simi_s[2][32];                // 512 B

    const int t0 = threadIdx.x;
    const int w = t0 >> 6, l = t0 & 63, lr = l & 15, lk = l >> 4;
    const size_t blk0 = (size_t)blockIdx.x * (TILES * 32);

    // ---- route(tile tt) on waves 0-1: full r15 body, outputs into buffer tt&1 ----
    auto do_route = [&](int tt) {
        const int g = lk, pixl = lr, buf = tt & 1;
        const size_t gpix = blk0 + (size_t)tt * 32 + w * 16 + pixl;
        unsigned short* pfb = pf_lds[buf];
        float apre = a_pre[0], apost = a_post[0], ares = a_res[0];
        float msk = p_mask[gpix];
        float bp0 = b_pre[0], bp1 = b_pre[1], bp2 = b_pre[2], bp3 = b_pre[3];
        float bq0 = b_post[0], bq1 = b_post[1], bq2 = b_post[2], bq3 = b_post[3];
        int mrow = (g + 2) & 3;
        float br0 = b_res[mrow*4+0], br1 = b_res[mrow*4+1], br2 = b_res[mrow*4+2], br3 = b_res[mrow*4+3];

        float s = 0.f, ss = 0.f;
        s16x8 pf[4];
        const float* prow = p + gpix * 128 + g * 8;
        #pragma unroll
        for (int kk = 0; kk < 4; ++kk) {
            float4 va = *(const float4*)(prow + kk * 32);
            float4 vb = *(const float4*)(prow + kk * 32 + 4);
            s  += va.x + va.y + va.z + va.w + vb.x + vb.y + vb.z + vb.w;
            ss += va.x*va.x + va.y*va.y + va.z*va.z + va.w*va.w
                + vb.x*vb.x + vb.y*vb.y + vb.z*vb.z + vb.w*vb.w;
            union { s16x8 v; uint32_t u[4]; } cc;
            cc.u[0] = pack2(va.x, va.y);
            cc.u[1] = pack2(va.z, va.w);
            cc.u[2] = pack2(vb.x, vb.y);
            cc.u[3] = pack2(vb.z, vb.w);
            pf[kk] = cc.v;
            *(s16x8*)(pfb + (size_t)(w * 4 + kk) * 512 + l * 8) = cc.v;
        }
        s  += __shfl_xor(s, 16);  ss += __shfl_xor(ss, 16);
        s  += __shfl_xor(s, 32);  ss += __shfl_xor(ss, 32);
        float mu = s * (1.f / 128.f), mq = ss * (1.f / 128.f);
        float rv  = rsqrtf(mq + 1.1920929e-07f);
        float var = mq - mu * mu;

        f32x4 y1 = {0.f, 0.f, 0.f, 0.f}, y2 = {0.f, 0.f, 0.f, 0.f};
        #pragma unroll
        for (int kk = 0; kk < 4; ++kk) {
            s16x8 a0 = *(const s16x8*)(g_wefff + ((size_t)(kk) * 64 + l) * 8);
            s16x8 a1 = *(const s16x8*)(g_wefff + ((size_t)(4 + kk) * 64 + l) * 8);
            y1 = MFMA16(a0, pf[kk], y1);
            y2 = MFMA16(a1, pf[kk], y2);
        }
        #pragma unroll
        for (int r = 0; r < 4; ++r) { y1[r] *= rv; y2[r] *= rv; }

        float sp_loc = fast_sig(apre * fast_tanh(y1[0]) + bp0)
                     + fast_sig(apre * fast_tanh(y1[1]) + bp1)
                     + fast_sig(apre * fast_tanh(y1[2]) + bp2)
                     + fast_sig(apre * fast_tanh(y1[3]) + bp3);
        float sp = __shfl(sp_loc, pixl);

        float hp0 = 2.f * fast_sig(apost * fast_tanh(y1[0]) + bq0);
        float hp1 = 2.f * fast_sig(apost * fast_tanh(y1[1]) + bq1);
        float hp2 = 2.f * fast_sig(apost * fast_tanh(y1[2]) + bq2);
        float hp3 = 2.f * fast_sig(apost * fast_tanh(y1[3]) + bq3);

        bool lo = g < 2;
        float M0 = __expf(ares * fast_tanh(lo ? y2[0] : y1[0]) + br0);
        float M1 = __expf(ares * fast_tanh(lo ? y2[1] : y1[1]) + br1);
        float M2 = __expf(ares * fast_tanh(lo ? y2[2] : y1[2]) + br2);
        float M3 = __expf(ares * fast_tanh(lo ? y2[3] : y1[3]) + br3);
        #pragma unroll 1
        for (int it = 0; it < 20; ++it) {
            float ri = __builtin_amdgcn_rcpf(M0 + M1 + M2 + M3);
            M0 *= ri; M1 *= ri; M2 *= ri; M3 *= ri;
            float c0 = M0, c1 = M1, c2 = M2, c3 = M3;
            c0 += __shfl_xor(c0, 16); c1 += __shfl_xor(c1, 16); c2 += __shfl_xor(c2, 16); c3 += __shfl_xor(c3, 16);
            c0 += __shfl_xor(c0, 32); c1 += __shfl_xor(c1, 32); c2 += __shfl_xor(c2, 32); c3 += __shfl_xor(c3, 32);
            M0 *= __builtin_amdgcn_rcpf(c0); M1 *= __builtin_amdgcn_rcpf(c1);
            M2 *= __builtin_amdgcn_rcpf(c2); M3 *= __builtin_amdgcn_rcpf(c3);
        }
        float rm = M0 + M1 + M2 + M3;

        float h0b = __shfl(hp0, pixl + 16);
        float h1b = __shfl(hp1, pixl + 16);
        float h2b = __shfl(hp2, pixl + 16);
        float h3b = __shfl(hp3, pixl + 16);
        float hpm = (mrow & 2) ? ((mrow & 1) ? h3b : h2b) : ((mrow & 1) ? h1b : h0b);

        int pix = w * 16 + pixl;
        A_s[buf][pix * 4 + mrow] = rm + hpm * sp;
        B_s[buf][pix * 4 + mrow] = hpm * msk;
        if (l < 16) {
            float istd = rsqrtf(sp * sp * var + 1e-5f);
            simi_s[buf][pix] = make_float2(sp * istd, sp * mu * istd);
        }
    };

    // ---- prologue: route tile 0 ----
    if (w < 2) do_route(0);
    SYNCB();

    #pragma unroll 1
    for (int tt = 0; tt < TILES; ++tt) {
        const int buf = tt & 1;
        const int wm = w - 2;

        // ==== segment 1: route(tt+1) on w0-1  ||  GEMM1(tt)+fold on w2-9 ====
        if (w < 2) {
            if (tt + 1 < TILES) do_route(tt + 1);
        } else {
            const unsigned short* pfb = pf_lds[buf];
            s16x8 pfr[2][4];
            #pragma unroll
            for (int it = 0; it < 2; ++it)
                #pragma unroll
                for (int kk = 0; kk < 4; ++kk)
                    pfr[it][kk] = *(const s16x8*)(pfb + (size_t)(it * 4 + kk) * 512 + l * 8);

            f32x4 acc1[4][2] = {};
            #pragma unroll
            for (int kk = 0; kk < 4; ++kk)
                #pragma unroll
                for (int jt = 0; jt < 4; ++jt) {
                    s16x8 a = *(const s16x8*)(g_w1gf + ((size_t)((wm * 4 + jt) * 4 + kk) * 64 + l) * 8);
                    acc1[jt][0] = MFMA16(a, pfr[0][kk], acc1[jt][0]);
                    acc1[jt][1] = MFMA16(a, pfr[1][kk], acc1[jt][1]);
                }

            float2 sim0 = simi_s[buf][lr];
            float2 sim1 = simi_s[buf][16 + lr];
            #pragma unroll
            for (int jt = 0; jt < 4; ++jt) {
                int j0 = wm * 64 + jt * 16 + lk * 4;
                float4 wg = *(const float4*)(g_w1gs + j0);
                float4 ha = *(const float4*)(g_hA + j0);
                int ksg = wm * 2 + (jt >> 1);
                int laneB = lr + 16 * ((jt & 1) * 2 + (lk >> 1));
                #pragma unroll
                for (int it = 0; it < 2; ++it) {
                    float si = it ? sim1.x : sim0.x;
                    float mi = it ? sim1.y : sim0.y;
                    f32x4 v = acc1[jt][it];
                    float h0 = fmaxf(fmaf(si, v[0], fmaf(-mi, wg.x, ha.x)), 0.f);
                    float h1 = fmaxf(fmaf(si, v[1], fmaf(-mi, wg.y, ha.y)), 0.f);
                    float h2 = fmaxf(fmaf(si, v[2], fmaf(-mi, wg.z, ha.z)), 0.f);
                    float h3 = fmaxf(fmaf(si, v[3], fmaf(-mi, wg.w, ha.w)), 0.f);
                    uint2 uu;
                    uu.x = pack2(h0, h1);
                    uu.y = pack2(h2, h3);
                    *(uint2*)(h16 + (size_t)(ksg * 2 + it) * 512 + laneB * 8 + (lk & 1) * 4) = uu;
                }
            }
        }
        SYNCB();   // h16(tt) ready; route(tt+1) results published

        // ==== segment 2: GEMM2(tt) + epilogue(tt) on w2-9 ====
        if (w >= 2) {
            f32x4 acc2[2] = {};
            #pragma unroll 4
            for (int ksg = 0; ksg < 16; ++ksg) {
                s16x8 a  = *(const s16x8*)(g_w2f16 + ((size_t)(ksg * 8 + wm) * 64 + l) * 8);
                s16x8 b0 = *(const s16x8*)(h16 + (size_t)(ksg * 2 + 0) * 512 + l * 8);
                s16x8 b1 = *(const s16x8*)(h16 + (size_t)(ksg * 2 + 1) * 512 + l * 8);
                acc2[0] = MFMA16(a, b0, acc2[0]);
                acc2[1] = MFMA16(a, b1, acc2[1]);
            }
            const int c0 = wm * 16 + lk * 4;
            float4 b2v = *(const float4*)(b2g + c0);
            const unsigned short* pfb = pf_lds[buf];
            #pragma unroll
            for (int it = 0; it < 2; ++it) {
                int i = it * 16 + lr;
                f32x4 Av = *(const f32x4*)(A_s[buf] + i * 4);
                f32x4 Bv = *(const f32x4*)(B_s[buf] + i * 4);
                const unsigned short* pe = pfb
                    + ((size_t)(it * 4 + (wm >> 1)) * 64 + ((wm & 1) * 2 + (lk >> 1)) * 16 + lr) * 8
                    + (lk & 1) * 4;
                uint2 pb = *(const uint2*)pe;
                float p0 = bf2f(pb.x & 0xffffu), p1 = __uint_as_float(pb.x & 0xffff0000u);
                float p2 = bf2f(pb.y & 0xffffu), p3 = __uint_as_float(pb.y & 0xffff0000u);
                float d0 = acc2[it][0] + b2v.x, d1 = acc2[it][1] + b2v.y;
                float d2 = acc2[it][2] + b2v.z, d3 = acc2[it][3] + b2v.w;
                float* og = out + (blk0 + (size_t)tt * 32 + i) * 512 + c0;
                #pragma unroll
                for (int m = 0; m < 4; ++m) {
                    f32x4 o;
                    o[0] = Av[m] * p0 + Bv[m] * d0;
                    o[1] = Av[m] * p1 + Bv[m] * d1;
                    o[2] = Av[m] * p2 + Bv[m] * d2;
                    o[3] = Av[m] * p3 + Bv[m] * d3;
                    *(f32x4*)(og + m * 128) = o;
                }
            }
        }
        SYNCB();   // h16 consumed; safe to overwrite next iteration
    }
}

extern "C" void kernel_launch(void* const* d_in, const int* in_sizes, int n_in,
                              void* d_out, int out_size, void* d_ws, size_t ws_size,
                              hipStream_t stream) {
    const float* p      = (const float*)d_in[0];
    const float* p_mask = (const float*)d_in[1];
    const float* W_pre  = (const float*)d_in[2];
    const float* W_post = (const float*)d_in[3];
    const float* W_res  = (const float*)d_in[4];
    const float* b_pre  = (const float*)d_in[5];
    const float* b_post = (const float*)d_in[6];
    const float* b_res  = (const float*)d_in[7];
    const float* a_pre  = (const float*)d_in[8];
    const float* a_post = (const float*)d_in[9];
    const float* a_res  = (const float*)d_in[10];
    const float* ln_g   = (const float*)d_in[11];
    const float* ln_b   = (const float*)d_in[12];
    const float* W1     = (const float*)d_in[13];
    const float* b1     = (const float*)d_in[14];
    const float* W2     = (const float*)d_in[15];
    const float* b2     = (const float*)d_in[16];
    float* out = (float*)d_out;

    prep_kernel<<<265, 512, 0, stream>>>(W_pre, W_post, W_res, W1, W2, ln_g, ln_b, b1);
    fused_kernel<<<NBLK, 640, 0, stream>>>(p, p_mask, b_pre, b_post, b_res,
                                           a_pre, a_post, a_res, b2, out);
}

// Round 18
// 92.808 us; speedup vs baseline: 1.3968x; 1.0526x over previous
//
#include <hip/hip_runtime.h>
#include <stdint.h>

// Problem constants (B=1, L=256, C=128, N=4, TN=4)
#define LLTOT 65536
#define CDIM  128
#define TILES 4
#define NBLK  (LLTOT / (TILES * 32))   // 512 blocks, 640 threads (10 waves)

typedef float f32x4 __attribute__((ext_vector_type(4)));
typedef short s16x8 __attribute__((ext_vector_type(8)));

#define MFMA16(a, b, c) __builtin_amdgcn_mfma_f32_16x16x32_bf16((a), (b), (c), 0, 0, 0)

// lgkm-only barrier: LDS coherence without draining global stores
#define SYNCB() do {                                        \
    __builtin_amdgcn_sched_barrier(0);                      \
    asm volatile("s_waitcnt lgkmcnt(0)" ::: "memory");      \
    __builtin_amdgcn_s_barrier();                           \
    __builtin_amdgcn_sched_barrier(0);                      \
} while (0)

// ---- persistent device scratch (weights only) ----
__device__ __align__(16) unsigned short g_wefff[2 * 4 * 64 * 8];
__device__ __align__(16) unsigned short g_w1gf[32 * 4 * 64 * 8];
__device__ __align__(16) unsigned short g_w2f16[16 * 8 * 64 * 8];
__device__ __align__(16) float  g_hA[512];
__device__ __align__(16) float  g_w1gs[512];

__device__ __forceinline__ unsigned short f2bf(float f) {
    union { float f; uint32_t u; } v; v.f = f;
    uint32_t u = v.u;
    return (unsigned short)((u + 0x7FFFu + ((u >> 16) & 1u)) >> 16);
}
__device__ __forceinline__ uint32_t pack2(float a, float b) {
    uint32_t r;
    asm("v_cvt_pk_bf16_f32 %0, %1, %2" : "=v"(r) : "v"(a), "v"(b));
    return r;
}
__device__ __forceinline__ float bf2f(uint32_t lo16) { return __uint_as_float(lo16 << 16); }

__device__ __forceinline__ float fast_tanh(float x) {
    float cx = fminf(fmaxf(x, -10.f), 10.f);
    float e = __expf(2.f * cx);
    return (e - 1.f) * __builtin_amdgcn_rcpf(e + 1.f);
}
__device__ __forceinline__ float fast_sig(float z) {
    return __builtin_amdgcn_rcpf(1.f + __expf(-z));
}

// ---- prep (identical to r17) ----
__global__ void prep_kernel(const float* __restrict__ Wpre, const float* __restrict__ Wpost,
                            const float* __restrict__ Wres, const float* __restrict__ W1,
                            const float* __restrict__ W2, const float* __restrict__ ln_g,
                            const float* __restrict__ ln_b, const float* __restrict__ b1) {
    int b = blockIdx.x, t = threadIdx.x;
    if (b == 264) {
        int j = t;
        float sg = 0.f, sb = 0.f;
        const float* row = W1 + j * 128;
        #pragma unroll 4
        for (int c = 0; c < 128; c += 4) {
            float4 wv = *(const float4*)(row + c);
            float4 gv = *(const float4*)(ln_g + c);
            float4 bv = *(const float4*)(ln_b + c);
            sg += wv.x*gv.x + wv.y*gv.y + wv.z*gv.z + wv.w*gv.w;
            sb += wv.x*bv.x + wv.y*bv.y + wv.z*bv.z + wv.w*bv.w;
        }
        g_hA[j]   = b1[j] + sb;
        g_w1gs[j] = sg;
        return;
    }
    int idx = b * 512 + t;
    if (idx < 4096) {
        int e = idx & 7, lane = (idx >> 3) & 63, kk = (idx >> 9) & 3, tile = idx >> 11;
        int o = tile * 16 + (lane & 15);
        int c = kk * 32 + (lane >> 4) * 8 + e;
        float v = 0.f;
        if (o < 4)        v = Wpre[o*512+c] + Wpre[o*512+128+c] + Wpre[o*512+256+c] + Wpre[o*512+384+c];
        else if (o < 8)   { int j = o - 4;  v = Wpost[j*512+c] + Wpost[j*512+128+c] + Wpost[j*512+256+c] + Wpost[j*512+384+c]; }
        else if (o < 24)  { int j = o - 8;  v = Wres[j*512+c] + Wres[j*512+128+c] + Wres[j*512+256+c] + Wres[j*512+384+c]; }
        g_wefff[idx] = f2bf(v);
    } else if (idx < 69632) {
        int d = idx - 4096;
        int e = d & 7, lane = (d >> 3) & 63, kk = (d >> 9) & 3, jt = d >> 11;
        int j = jt * 16 + (lane & 15);
        int c = kk * 32 + (lane >> 4) * 8 + e;
        g_w1gf[d] = f2bf(W1[j * 128 + c] * ln_g[c]);
    } else if (idx < 135168) {
        int d = idx - 69632;   // [ksg][ct][lane][8]
        int e = d & 7, lane = (d >> 3) & 63, ct = (d >> 9) & 7, ksg = d >> 12;
        int c = ct * 16 + (lane & 15);
        int k = ksg * 32 + (lane >> 4) * 8 + e;
        g_w2f16[d] = f2bf(W2[c * 512 + k]);
    }
}

// ---- fused: 10 waves; waves 0-1 route(t+1) while waves 2-9 MLP(t); 2 lgkm-barriers/tile ----
// __launch_bounds__(640, 1): the ONLY change vs r17 — removes the implicit 64-VGPR cap.
__global__ void __launch_bounds__(640, 1) fused_kernel(
    const float* __restrict__ p, const float* __restrict__ p_mask,
    const float* __restrict__ b_pre, const float* __restrict__ b_post, const float* __restrict__ b_res,
    const float* __restrict__ a_pre, const float* __restrict__ a_post, const float* __restrict__ a_res,
    const float* __restrict__ b2g, float* __restrict__ out)
{
    __shared__ __align__(16) unsigned short pf_lds[2][8 * 512];   // 16 KB: p frags, dbuf
    __shared__ __align__(16) unsigned short h16[32 * 512];        // 32 KB: h B-frags [ksg*2+it][lane][8]
    __shared__ __align__(16) float A_s[2][128], B_s[2][128];      // 2 KB
    __shared__ __align__(16) float2 simi_s[2][32];                // 512 B

    const int t0 = threadIdx.x;
    const int w = t0 >> 6, l = t0 & 63, lr = l & 15, lk = l >> 4;
    const size_t blk0 = (size_t)blockIdx.x * (TILES * 32);

    // ---- route(tile tt) on waves 0-1: full r15 body, outputs into buffer tt&1 ----
    auto do_route = [&](int tt) {
        const int g = lk, pixl = lr, buf = tt & 1;
        const size_t gpix = blk0 + (size_t)tt * 32 + w * 16 + pixl;
        unsigned short* pfb = pf_lds[buf];
        float apre = a_pre[0], apost = a_post[0], ares = a_res[0];
        float msk = p_mask[gpix];
        float bp0 = b_pre[0], bp1 = b_pre[1], bp2 = b_pre[2], bp3 = b_pre[3];
        float bq0 = b_post[0], bq1 = b_post[1], bq2 = b_post[2], bq3 = b_post[3];
        int mrow = (g + 2) & 3;
        float br0 = b_res[mrow*4+0], br1 = b_res[mrow*4+1], br2 = b_res[mrow*4+2], br3 = b_res[mrow*4+3];

        float s = 0.f, ss = 0.f;
        s16x8 pf[4];
        const float* prow = p + gpix * 128 + g * 8;
        #pragma unroll
        for (int kk = 0; kk < 4; ++kk) {
            float4 va = *(const float4*)(prow + kk * 32);
            float4 vb = *(const float4*)(prow + kk * 32 + 4);
            s  += va.x + va.y + va.z + va.w + vb.x + vb.y + vb.z + vb.w;
            ss += va.x*va.x + va.y*va.y + va.z*va.z + va.w*va.w
                + vb.x*vb.x + vb.y*vb.y + vb.z*vb.z + vb.w*vb.w;
            union { s16x8 v; uint32_t u[4]; } cc;
            cc.u[0] = pack2(va.x, va.y);
            cc.u[1] = pack2(va.z, va.w);
            cc.u[2] = pack2(vb.x, vb.y);
            cc.u[3] = pack2(vb.z, vb.w);
            pf[kk] = cc.v;
            *(s16x8*)(pfb + (size_t)(w * 4 + kk) * 512 + l * 8) = cc.v;
        }
        s  += __shfl_xor(s, 16);  ss += __shfl_xor(ss, 16);
        s  += __shfl_xor(s, 32);  ss += __shfl_xor(ss, 32);
        float mu = s * (1.f / 128.f), mq = ss * (1.f / 128.f);
        float rv  = rsqrtf(mq + 1.1920929e-07f);
        float var = mq - mu * mu;

        f32x4 y1 = {0.f, 0.f, 0.f, 0.f}, y2 = {0.f, 0.f, 0.f, 0.f};
        #pragma unroll
        for (int kk = 0; kk < 4; ++kk) {
            s16x8 a0 = *(const s16x8*)(g_wefff + ((size_t)(kk) * 64 + l) * 8);
            s16x8 a1 = *(const s16x8*)(g_wefff + ((size_t)(4 + kk) * 64 + l) * 8);
            y1 = MFMA16(a0, pf[kk], y1);
            y2 = MFMA16(a1, pf[kk], y2);
        }
        #pragma unroll
        for (int r = 0; r < 4; ++r) { y1[r] *= rv; y2[r] *= rv; }

        float sp_loc = fast_sig(apre * fast_tanh(y1[0]) + bp0)
                     + fast_sig(apre * fast_tanh(y1[1]) + bp1)
                     + fast_sig(apre * fast_tanh(y1[2]) + bp2)
                     + fast_sig(apre * fast_tanh(y1[3]) + bp3);
        float sp = __shfl(sp_loc, pixl);

        float hp0 = 2.f * fast_sig(apost * fast_tanh(y1[0]) + bq0);
        float hp1 = 2.f * fast_sig(apost * fast_tanh(y1[1]) + bq1);
        float hp2 = 2.f * fast_sig(apost * fast_tanh(y1[2]) + bq2);
        float hp3 = 2.f * fast_sig(apost * fast_tanh(y1[3]) + bq3);

        bool lo = g < 2;
        float M0 = __expf(ares * fast_tanh(lo ? y2[0] : y1[0]) + br0);
        float M1 = __expf(ares * fast_tanh(lo ? y2[1] : y1[1]) + br1);
        float M2 = __expf(ares * fast_tanh(lo ? y2[2] : y1[2]) + br2);
        float M3 = __expf(ares * fast_tanh(lo ? y2[3] : y1[3]) + br3);
        #pragma unroll 1
        for (int it = 0; it < 20; ++it) {
            float ri = __builtin_amdgcn_rcpf(M0 + M1 + M2 + M3);
            M0 *= ri; M1 *= ri; M2 *= ri; M3 *= ri;
            float c0 = M0, c1 = M1, c2 = M2, c3 = M3;
            c0 += __shfl_xor(c0, 16); c1 += __shfl_xor(c1, 16); c2 += __shfl_xor(c2, 16); c3 += __shfl_xor(c3, 16);
            c0 += __shfl_xor(c0, 32); c1 += __shfl_xor(c1, 32); c2 += __shfl_xor(c2, 32); c3 += __shfl_xor(c3, 32);
            M0 *= __builtin_amdgcn_rcpf(c0); M1 *= __builtin_amdgcn_rcpf(c1);
            M2 *= __builtin_amdgcn_rcpf(c2); M3 *= __builtin_amdgcn_rcpf(c3);
        }
        float rm = M0 + M1 + M2 + M3;

        float h0b = __shfl(hp0, pixl + 16);
        float h1b = __shfl(hp1, pixl + 16);
        float h2b = __shfl(hp2, pixl + 16);
        float h3b = __shfl(hp3, pixl + 16);
        float hpm = (mrow & 2) ? ((mrow & 1) ? h3b : h2b) : ((mrow & 1) ? h1b : h0b);

        int pix = w * 16 + pixl;
        A_s[buf][pix * 4 + mrow] = rm + hpm * sp;
        B_s[buf][pix * 4 + mrow] = hpm * msk;
        if (l < 16) {
            float istd = rsqrtf(sp * sp * var + 1e-5f);
            simi_s[buf][pix] = make_float2(sp * istd, sp * mu * istd);
        }
    };

    // ---- prologue: route tile 0 ----
    if (w < 2) do_route(0);
    SYNCB();

    #pragma unroll 1
    for (int tt = 0; tt < TILES; ++tt) {
        const int buf = tt & 1;
        const int wm = w - 2;

        // ==== segment 1: route(tt+1) on w0-1  ||  GEMM1(tt)+fold on w2-9 ====
        if (w < 2) {
            if (tt + 1 < TILES) do_route(tt + 1);
        } else {
            const unsigned short* pfb = pf_lds[buf];
            s16x8 pfr[2][4];
            #pragma unroll
            for (int it = 0; it < 2; ++it)
                #pragma unroll
                for (int kk = 0; kk < 4; ++kk)
                    pfr[it][kk] = *(const s16x8*)(pfb + (size_t)(it * 4 + kk) * 512 + l * 8);

            f32x4 acc1[4][2] = {};
            #pragma unroll
            for (int kk = 0; kk < 4; ++kk)
                #pragma unroll
                for (int jt = 0; jt < 4; ++jt) {
                    s16x8 a = *(const s16x8*)(g_w1gf + ((size_t)((wm * 4 + jt) * 4 + kk) * 64 + l) * 8);
                    acc1[jt][0] = MFMA16(a, pfr[0][kk], acc1[jt][0]);
                    acc1[jt][1] = MFMA16(a, pfr[1][kk], acc1[jt][1]);
                }

            float2 sim0 = simi_s[buf][lr];
            float2 sim1 = simi_s[buf][16 + lr];
            #pragma unroll
            for (int jt = 0; jt < 4; ++jt) {
                int j0 = wm * 64 + jt * 16 + lk * 4;
                float4 wg = *(const float4*)(g_w1gs + j0);
                float4 ha = *(const float4*)(g_hA + j0);
                int ksg = wm * 2 + (jt >> 1);
                int laneB = lr + 16 * ((jt & 1) * 2 + (lk >> 1));
                #pragma unroll
                for (int it = 0; it < 2; ++it) {
                    float si = it ? sim1.x : sim0.x;
                    float mi = it ? sim1.y : sim0.y;
                    f32x4 v = acc1[jt][it];
                    float h0 = fmaxf(fmaf(si, v[0], fmaf(-mi, wg.x, ha.x)), 0.f);
                    float h1 = fmaxf(fmaf(si, v[1], fmaf(-mi, wg.y, ha.y)), 0.f);
                    float h2 = fmaxf(fmaf(si, v[2], fmaf(-mi, wg.z, ha.z)), 0.f);
                    float h3 = fmaxf(fmaf(si, v[3], fmaf(-mi, wg.w, ha.w)), 0.f);
                    uint2 uu;
                    uu.x = pack2(h0, h1);
                    uu.y = pack2(h2, h3);
                    *(uint2*)(h16 + (size_t)(ksg * 2 + it) * 512 + laneB * 8 + (lk & 1) * 4) = uu;
                }
            }
        }
        SYNCB();   // h16(tt) ready; route(tt+1) results published

        // ==== segment 2: GEMM2(tt) + epilogue(tt) on w2-9 ====
        if (w >= 2) {
            f32x4 acc2[2] = {};
            #pragma unroll 4
            for (int ksg = 0; ksg < 16; ++ksg) {
                s16x8 a  = *(const s16x8*)(g_w2f16 + ((size_t)(ksg * 8 + wm) * 64 + l) * 8);
                s16x8 b0 = *(const s16x8*)(h16 + (size_t)(ksg * 2 + 0) * 512 + l * 8);
                s16x8 b1 = *(const s16x8*)(h16 + (size_t)(ksg * 2 + 1) * 512 + l * 8);
                acc2[0] = MFMA16(a, b0, acc2[0]);
                acc2[1] = MFMA16(a, b1, acc2[1]);
            }
            const int c0 = wm * 16 + lk * 4;
            float4 b2v = *(const float4*)(b2g + c0);
            const unsigned short* pfb = pf_lds[buf];
            #pragma unroll
            for (int it = 0; it < 2; ++it) {
                int i = it * 16 + lr;
                f32x4 Av = *(const f32x4*)(A_s[buf] + i * 4);
                f32x4 Bv = *(const f32x4*)(B_s[buf] + i * 4);
                const unsigned short* pe = pfb
                    + ((size_t)(it * 4 + (wm >> 1)) * 64 + ((wm & 1) * 2 + (lk >> 1)) * 16 + lr) * 8
                    + (lk & 1) * 4;
                uint2 pb = *(const uint2*)pe;
                float p0 = bf2f(pb.x & 0xffffu), p1 = __uint_as_float(pb.x & 0xffff0000u);
                float p2 = bf2f(pb.y & 0xffffu), p3 = __uint_as_float(pb.y & 0xffff0000u);
                float d0 = acc2[it][0] + b2v.x, d1 = acc2[it][1] + b2v.y;
                float d2 = acc2[it][2] + b2v.z, d3 = acc2[it][3] + b2v.w;
                float* og = out + (blk0 + (size_t)tt * 32 + i) * 512 + c0;
                #pragma unroll
                for (int m = 0; m < 4; ++m) {
                    f32x4 o;
                    o[0] = Av[m] * p0 + Bv[m] * d0;
                    o[1] = Av[m] * p1 + Bv[m] * d1;
                    o[2] = Av[m] * p2 + Bv[m] * d2;
                    o[3] = Av[m] * p3 + Bv[m] * d3;
                    *(f32x4*)(og + m * 128) = o;
                }
            }
        }
        SYNCB();   // h16 consumed; safe to overwrite next iteration
    }
}

extern "C" void kernel_launch(void* const* d_in, const int* in_sizes, int n_in,
                              void* d_out, int out_size, void* d_ws, size_t ws_size,
                              hipStream_t stream) {
    const float* p      = (const float*)d_in[0];
    const float* p_mask = (const float*)d_in[1];
    const float* W_pre  = (const float*)d_in[2];
    const float* W_post = (const float*)d_in[3];
    const float* W_res  = (const float*)d_in[4];
    const float* b_pre  = (const float*)d_in[5];
    const float* b_post = (const float*)d_in[6];
    const float* b_res  = (const float*)d_in[7];
    const float* a_pre  = (const float*)d_in[8];
    const float* a_post = (const float*)d_in[9];
    const float* a_res  = (const float*)d_in[10];
    const float* ln_g   = (const float*)d_in[11];
    const float* ln_b   = (const float*)d_in[12];
    const float* W1     = (const float*)d_in[13];
    const float* b1     = (const float*)d_in[14];
    const float* W2     = (const float*)d_in[15];
    const float* b2     = (const float*)d_in[16];
    float* out = (float*)d_out;

    prep_kernel<<<265, 512, 0, stream>>>(W_pre, W_post, W_res, W1, W2, ln_g, ln_b, b1);
    fused_kernel<<<NBLK, 640, 0, stream>>>(p, p_mask, b_pre, b_post, b_res,
                                           a_pre, a_post, a_res, b2, out);
}

// Round 19
// 75.312 us; speedup vs baseline: 1.7213x; 1.2323x over previous
//
#include <hip/hip_runtime.h>
#include <stdint.h>

// Problem constants (B=1, L=256, C=128, N=4, TN=4)
#define LLTOT 65536
#define CDIM  128
#define TPIX  32

typedef float f32x4  __attribute__((ext_vector_type(4)));
typedef float f32x16 __attribute__((ext_vector_type(16)));
typedef short s16x8  __attribute__((ext_vector_type(8)));

#define MFMA16(a, b, c) __builtin_amdgcn_mfma_f32_16x16x32_bf16((a), (b), (c), 0, 0, 0)
#define MFMA32(a, b, c) __builtin_amdgcn_mfma_f32_32x32x16_bf16((a), (b), (c), 0, 0, 0)

#define RPAD 132   // f32 row stride for D buffers (128 + 4 to break bank pattern)

// ---- persistent device scratch (weights only) ----
__device__ __align__(16) unsigned short g_wefff[2 * 4 * 64 * 8];
__device__ __align__(16) unsigned short g_w1gf[32 * 4 * 64 * 8];
__device__ __align__(16) unsigned short g_w2f [4 * 32 * 64 * 8];
__device__ __align__(16) float  g_hA[512];
__device__ __align__(16) float  g_w1gs[512];

__device__ __forceinline__ unsigned short f2bf(float f) {
    union { float f; uint32_t u; } v; v.f = f;
    uint32_t u = v.u;
    return (unsigned short)((u + 0x7FFFu + ((u >> 16) & 1u)) >> 16);
}
__device__ __forceinline__ uint32_t pack2(float a, float b) {
    uint32_t r;
    asm("v_cvt_pk_bf16_f32 %0, %1, %2" : "=v"(r) : "v"(a), "v"(b));
    return r;
}
__device__ __forceinline__ float bf2f(uint32_t lo16) { return __uint_as_float(lo16 << 16); }

__device__ __forceinline__ float fast_tanh(float x) {
    float cx = fminf(fmaxf(x, -10.f), 10.f);
    float e = __expf(2.f * cx);
    return (e - 1.f) * __builtin_amdgcn_rcpf(e + 1.f);
}
__device__ __forceinline__ float fast_sig(float z) {
    return __builtin_amdgcn_rcpf(1.f + __expf(-z));
}

// ---- prep ----
__global__ void prep_kernel(const float* __restrict__ Wpre, const float* __restrict__ Wpost,
                            const float* __restrict__ Wres, const float* __restrict__ W1,
                            const float* __restrict__ W2, const float* __restrict__ ln_g,
                            const float* __restrict__ ln_b, const float* __restrict__ b1) {
    int b = blockIdx.x, t = threadIdx.x;
    if (b == 264) {
        int j = t;
        float sg = 0.f, sb = 0.f;
        const float* row = W1 + j * 128;
        #pragma unroll 4
        for (int c = 0; c < 128; c += 4) {
            float4 wv = *(const float4*)(row + c);
            float4 gv = *(const float4*)(ln_g + c);
            float4 bv = *(const float4*)(ln_b + c);
            sg += wv.x*gv.x + wv.y*gv.y + wv.z*gv.z + wv.w*gv.w;
            sb += wv.x*bv.x + wv.y*bv.y + wv.z*bv.z + wv.w*bv.w;
        }
        g_hA[j]   = b1[j] + sb;
        g_w1gs[j] = sg;
        return;
    }
    int idx = b * 512 + t;
    if (idx < 4096) {
        int e = idx & 7, lane = (idx >> 3) & 63, kk = (idx >> 9) & 3, tile = idx >> 11;
        int o = tile * 16 + (lane & 15);
        int c = kk * 32 + (lane >> 4) * 8 + e;
        float v = 0.f;
        if (o < 4)        v = Wpre[o*512+c] + Wpre[o*512+128+c] + Wpre[o*512+256+c] + Wpre[o*512+384+c];
        else if (o < 8)   { int j = o - 4;  v = Wpost[j*512+c] + Wpost[j*512+128+c] + Wpost[j*512+256+c] + Wpost[j*512+384+c]; }
        else if (o < 24)  { int j = o - 8;  v = Wres[j*512+c] + Wres[j*512+128+c] + Wres[j*512+256+c] + Wres[j*512+384+c]; }
        g_wefff[idx] = f2bf(v);
    } else if (idx < 69632) {
        int d = idx - 4096;
        int e = d & 7, lane = (d >> 3) & 63, kk = (d >> 9) & 3, jt = d >> 11;
        int j = jt * 16 + (lane & 15);
        int c = kk * 32 + (lane >> 4) * 8 + e;
        g_w1gf[d] = f2bf(W1[j * 128 + c] * ln_g[c]);
    } else if (idx < 135168) {
        int d = idx - 69632;   // 32x32x16 A-fragment layout for W2
        int e = d & 7, lane = (d >> 3) & 63, kk = (d >> 9) & 31, ct = (d >> 14) & 3;
        int c = ct * 32 + (lane & 31);
        int k = kk * 16 + (lane >> 5) * 8 + e;
        g_w2f[d] = f2bf(W2[c * 512 + k]);
    }
}

// ---- fused: route | B1 | Sinkhorn + GEMM1 + fold | B2 | GEMM2(32x32) -> redA/redB | B3 | epilogue ----
__global__ void __launch_bounds__(512, 2) fused_kernel(
    const float* __restrict__ p, const float* __restrict__ p_mask,
    const float* __restrict__ b_pre, const float* __restrict__ b_post, const float* __restrict__ b_res,
    const float* __restrict__ a_pre, const float* __restrict__ a_post, const float* __restrict__ a_res,
    const float* __restrict__ b2g, float* __restrict__ out)
{
    __shared__ __align__(16) unsigned short pf_lds[8 * 64 * 8];   // 8 KB bf16 p fragments
    __shared__ __align__(16) unsigned short h32[32 * 64 * 8];     // 32 KB bf16 h, 32x32 B-fragment-linear
    __shared__ __align__(16) float redA[32 * RPAD];               // 16.9 KB D partial (k-half 0), [pix][c]
    __shared__ __align__(16) float redB[32 * RPAD];               // 16.9 KB D partial (k-half 1)
    __shared__ __align__(16) float A_s[128], B_s[128];
    __shared__ __align__(16) float2 simi_s[32];

    const int t = threadIdx.x;
    const int w = t >> 6, l = t & 63, lr = l & 15, lk = l >> 4;
    const size_t base = (size_t)blockIdx.x * TPIX;

    float M0 = 0.f, M1 = 0.f, M2 = 0.f, M3 = 0.f, sp = 0.f, hpm = 0.f;
    int mrow = 0, pix = 0;

    // ======== fast-route (waves 0-1): pf, simi, B_s, M-init ========
    if (w < 2) {
        const int g = lk, pixl = lr;
        const size_t gpix = base + w * 16 + pixl;
        float apre = a_pre[0], apost = a_post[0], ares = a_res[0];
        float msk = p_mask[gpix];
        float bp0 = b_pre[0], bp1 = b_pre[1], bp2 = b_pre[2], bp3 = b_pre[3];
        float bq0 = b_post[0], bq1 = b_post[1], bq2 = b_post[2], bq3 = b_post[3];
        mrow = (g + 2) & 3;
        float br0 = b_res[mrow*4+0], br1 = b_res[mrow*4+1], br2 = b_res[mrow*4+2], br3 = b_res[mrow*4+3];

        float s = 0.f, ss = 0.f;
        s16x8 pf[4];
        const float* prow = p + gpix * 128 + g * 8;
        #pragma unroll
        for (int kk = 0; kk < 4; ++kk) {
            float4 va = *(const float4*)(prow + kk * 32);
            float4 vb = *(const float4*)(prow + kk * 32 + 4);
            s  += va.x + va.y + va.z + va.w + vb.x + vb.y + vb.z + vb.w;
            ss += va.x*va.x + va.y*va.y + va.z*va.z + va.w*va.w
                + vb.x*vb.x + vb.y*vb.y + vb.z*vb.z + vb.w*vb.w;
            union { s16x8 v; uint32_t u[4]; } cc;
            cc.u[0] = pack2(va.x, va.y);
            cc.u[1] = pack2(va.z, va.w);
            cc.u[2] = pack2(vb.x, vb.y);
            cc.u[3] = pack2(vb.z, vb.w);
            pf[kk] = cc.v;
            *(s16x8*)(pf_lds + (size_t)(w * 4 + kk) * 512 + l * 8) = cc.v;
        }
        s  += __shfl_xor(s, 16);  ss += __shfl_xor(ss, 16);
        s  += __shfl_xor(s, 32);  ss += __shfl_xor(ss, 32);
        float mu = s * (1.f / 128.f), mq = ss * (1.f / 128.f);
        float rv  = rsqrtf(mq + 1.1920929e-07f);
        float var = mq - mu * mu;

        f32x4 y1 = {0.f, 0.f, 0.f, 0.f}, y2 = {0.f, 0.f, 0.f, 0.f};
        #pragma unroll
        for (int kk = 0; kk < 4; ++kk) {
            s16x8 a0 = *(const s16x8*)(g_wefff + ((size_t)(kk) * 64 + l) * 8);
            s16x8 a1 = *(const s16x8*)(g_wefff + ((size_t)(4 + kk) * 64 + l) * 8);
            y1 = MFMA16(a0, pf[kk], y1);
            y2 = MFMA16(a1, pf[kk], y2);
        }
        #pragma unroll
        for (int r = 0; r < 4; ++r) { y1[r] *= rv; y2[r] *= rv; }

        float sp_loc = fast_sig(apre * fast_tanh(y1[0]) + bp0)
                     + fast_sig(apre * fast_tanh(y1[1]) + bp1)
                     + fast_sig(apre * fast_tanh(y1[2]) + bp2)
                     + fast_sig(apre * fast_tanh(y1[3]) + bp3);
        sp = __shfl(sp_loc, pixl);

        float hp0 = 2.f * fast_sig(apost * fast_tanh(y1[0]) + bq0);
        float hp1 = 2.f * fast_sig(apost * fast_tanh(y1[1]) + bq1);
        float hp2 = 2.f * fast_sig(apost * fast_tanh(y1[2]) + bq2);
        float hp3 = 2.f * fast_sig(apost * fast_tanh(y1[3]) + bq3);

        bool lo = g < 2;
        M0 = __expf(ares * fast_tanh(lo ? y2[0] : y1[0]) + br0);
        M1 = __expf(ares * fast_tanh(lo ? y2[1] : y1[1]) + br1);
        M2 = __expf(ares * fast_tanh(lo ? y2[2] : y1[2]) + br2);
        M3 = __expf(ares * fast_tanh(lo ? y2[3] : y1[3]) + br3);

        float h0b = __shfl(hp0, pixl + 16);
        float h1b = __shfl(hp1, pixl + 16);
        float h2b = __shfl(hp2, pixl + 16);
        float h3b = __shfl(hp3, pixl + 16);
        hpm = (mrow & 2) ? ((mrow & 1) ? h3b : h2b) : ((mrow & 1) ? h1b : h0b);

        pix = w * 16 + pixl;
        B_s[pix * 4 + mrow] = hpm * msk;
        if (l < 16) {
            float istd = rsqrtf(sp * sp * var + 1e-5f);
            simi_s[pix] = make_float2(sp * istd, sp * mu * istd);
        }
    }
    __syncthreads();   // B1: pf + simi + B_s ready

    // ======== Sinkhorn on waves 0-1 (overlaps other waves' GEMM1) ========
    if (w < 2) {
        #pragma unroll 1
        for (int it = 0; it < 20; ++it) {
            float ri = __builtin_amdgcn_rcpf(M0 + M1 + M2 + M3);
            M0 *= ri; M1 *= ri; M2 *= ri; M3 *= ri;
            float c0 = M0, c1 = M1, c2 = M2, c3 = M3;
            c0 += __shfl_xor(c0, 16); c1 += __shfl_xor(c1, 16); c2 += __shfl_xor(c2, 16); c3 += __shfl_xor(c3, 16);
            c0 += __shfl_xor(c0, 32); c1 += __shfl_xor(c1, 32); c2 += __shfl_xor(c2, 32); c3 += __shfl_xor(c3, 32);
            M0 *= __builtin_amdgcn_rcpf(c0); M1 *= __builtin_amdgcn_rcpf(c1);
            M2 *= __builtin_amdgcn_rcpf(c2); M3 *= __builtin_amdgcn_rcpf(c3);
        }
        float rm = M0 + M1 + M2 + M3;
        A_s[pix * 4 + mrow] = rm + hpm * sp;
    }

    // ======== GEMM1 (single phase, pf in registers) ========
    s16x8 pfr[2][4];
    #pragma unroll
    for (int it = 0; it < 2; ++it)
        #pragma unroll
        for (int kk = 0; kk < 4; ++kk)
            pfr[it][kk] = *(const s16x8*)(pf_lds + (size_t)(it * 4 + kk) * 512 + l * 8);

    f32x4 acc1[4][2] = {};
    #pragma unroll
    for (int kk = 0; kk < 4; ++kk)
        #pragma unroll
        for (int jt = 0; jt < 4; ++jt) {
            s16x8 a = *(const s16x8*)(g_w1gf + ((size_t)((w * 4 + jt) * 4 + kk) * 64 + l) * 8);
            acc1[jt][0] = MFMA16(a, pfr[0][kk], acc1[jt][0]);
            acc1[jt][1] = MFMA16(a, pfr[1][kk], acc1[jt][1]);
        }

    // ======== fold -> h32 (32x32 B-fragment-linear layout) ========
    {
        float2 sim0 = simi_s[lr];
        float2 sim1 = simi_s[16 + lr];
        #pragma unroll
        for (int jt = 0; jt < 4; ++jt) {
            int j0 = w * 64 + jt * 16 + lk * 4;
            float4 wg = *(const float4*)(g_w1gs + j0);
            float4 ha = *(const float4*)(g_hA + j0);
            #pragma unroll
            for (int it = 0; it < 2; ++it) {
                float si = it ? sim1.x : sim0.x;
                float mi = it ? sim1.y : sim0.y;
                f32x4 v = acc1[jt][it];
                float h0 = fmaxf(fmaf(si, v[0], fmaf(-mi, wg.x, ha.x)), 0.f);
                float h1 = fmaxf(fmaf(si, v[1], fmaf(-mi, wg.y, ha.y)), 0.f);
                float h2 = fmaxf(fmaf(si, v[2], fmaf(-mi, wg.z, ha.z)), 0.f);
                float h3 = fmaxf(fmaf(si, v[3], fmaf(-mi, wg.w, ha.w)), 0.f);
                uint2 uu;
                uu.x = pack2(h0, h1);
                uu.y = pack2(h2, h3);
                uint32_t addr = (uint32_t)((w * 4 + jt) * 1024
                              + (it * 16 + lr + 32 * (lk >> 1)) * 16 + (lk & 1) * 8);
                *(uint2*)((char*)h32 + addr) = uu;
            }
        }
    }
    __syncthreads();   // B2: h32 ready

    // ======== GEMM2: 32x32x16, ct = w&3, k-half = w>>2 ; D partials -> redA/redB [pix][c] ========
    {
        const int ct = w & 3, kh = w >> 2;
        f32x16 acc2 = {0.f,0.f,0.f,0.f, 0.f,0.f,0.f,0.f, 0.f,0.f,0.f,0.f, 0.f,0.f,0.f,0.f};
        #pragma unroll 4
        for (int kk2 = 0; kk2 < 16; ++kk2) {
            int ks = kh * 16 + kk2;
            s16x8 a = *(const s16x8*)(g_w2f + ((size_t)(ct * 32 + ks) * 64 + l) * 8);
            s16x8 b = *(const s16x8*)(h32 + (size_t)ks * 512 + l * 8);
            acc2 = MFMA32(a, b, acc2);
        }
        float* red = kh ? redB : redA;
        int pixd = l & 31;
        #pragma unroll
        for (int q = 0; q < 4; ++q) {
            f32x4 v = {acc2[4*q+0], acc2[4*q+1], acc2[4*q+2], acc2[4*q+3]};
            int c = ct * 32 + 8 * q + 4 * (l >> 5);
            *(f32x4*)(red + pixd * RPAD + c) = v;
        }
    }
    __syncthreads();   // B3: D partials ready

    // ======== epilogue (all 8 waves, full-line stores) ========
    const int c0 = w * 16 + lk * 4;
    float4 b2v = *(const float4*)(b2g + c0);
    #pragma unroll
    for (int it = 0; it < 2; ++it) {
        int i = it * 16 + lr;
        f32x4 Av = *(const f32x4*)(A_s + i * 4);
        f32x4 Bv = *(const f32x4*)(B_s + i * 4);
        f32x4 Da = *(const f32x4*)(redA + i * RPAD + c0);
        f32x4 Db = *(const f32x4*)(redB + i * RPAD + c0);
        const unsigned short* pe = pf_lds
            + ((size_t)(it * 4 + (w >> 1)) * 64 + ((w & 1) * 2 + (lk >> 1)) * 16 + lr) * 8
            + (lk & 1) * 4;
        uint2 pb = *(const uint2*)pe;
        float p0 = bf2f(pb.x & 0xffffu), p1 = __uint_as_float(pb.x & 0xffff0000u);
        float p2 = bf2f(pb.y & 0xffffu), p3 = __uint_as_float(pb.y & 0xffff0000u);
        float d0 = Da[0] + Db[0] + b2v.x;
        float d1 = Da[1] + Db[1] + b2v.y;
        float d2 = Da[2] + Db[2] + b2v.z;
        float d3 = Da[3] + Db[3] + b2v.w;
        float* og = out + (base + i) * 512 + c0;
        #pragma unroll
        for (int m = 0; m < 4; ++m) {
            f32x4 o;
            o[0] = Av[m] * p0 + Bv[m] * d0;
            o[1] = Av[m] * p1 + Bv[m] * d1;
            o[2] = Av[m] * p2 + Bv[m] * d2;
            o[3] = Av[m] * p3 + Bv[m] * d3;
            *(f32x4*)(og + m * 128) = o;
        }
    }
}

extern "C" void kernel_launch(void* const* d_in, const int* in_sizes, int n_in,
                              void* d_out, int out_size, void* d_ws, size_t ws_size,
                              hipStream_t stream) {
    const float* p      = (const float*)d_in[0];
    const float* p_mask = (const float*)d_in[1];
    const float* W_pre  = (const float*)d_in[2];
    const float* W_post = (const float*)d_in[3];
    const float* W_res  = (const float*)d_in[4];
    const float* b_pre  = (const float*)d_in[5];
    const float* b_post = (const float*)d_in[6];
    const float* b_res  = (const float*)d_in[7];
    const float* a_pre  = (const float*)d_in[8];
    const float* a_post = (const float*)d_in[9];
    const float* a_res  = (const float*)d_in[10];
    const float* ln_g   = (const float*)d_in[11];
    const float* ln_b   = (const float*)d_in[12];
    const float* W1     = (const float*)d_in[13];
    const float* b1     = (const float*)d_in[14];
    const float* W2     = (const float*)d_in[15];
    const float* b2     = (const float*)d_in[16];
    float* out = (float*)d_out;

    prep_kernel<<<265, 512, 0, stream>>>(W_pre, W_post, W_res, W1, W2, ln_g, ln_b, b1);
    fused_kernel<<<2048, 512, 0, stream>>>(p, p_mask, b_pre, b_post, b_res,
                                           a_pre, a_post, a_res, b2, out);
}

// Round 20
// 71.072 us; speedup vs baseline: 1.8240x; 1.0597x over previous
//
#include <hip/hip_runtime.h>
#include <stdint.h>

// Problem constants (B=1, L=256, C=128, N=4, TN=4)
#define LLTOT 65536
#define CDIM  128
#define TPIX  32

typedef float f32x4  __attribute__((ext_vector_type(4)));
typedef float f32x16 __attribute__((ext_vector_type(16)));
typedef short s16x8  __attribute__((ext_vector_type(8)));

#define MFMA16(a, b, c) __builtin_amdgcn_mfma_f32_16x16x32_bf16((a), (b), (c), 0, 0, 0)
#define MFMA32(a, b, c) __builtin_amdgcn_mfma_f32_32x32x16_bf16((a), (b), (c), 0, 0, 0)

#define RPAD 132   // f32 row stride for D buffers (128 + 4 to break bank pattern)

// ---- persistent device scratch (weights only) ----
__device__ __align__(16) unsigned short g_wefff[2 * 4 * 64 * 8];
__device__ __align__(16) unsigned short g_w1gf[32 * 4 * 64 * 8];
__device__ __align__(16) unsigned short g_w2f [4 * 32 * 64 * 8];
__device__ __align__(16) float  g_hA[512];
__device__ __align__(16) float  g_w1gs[512];

__device__ __forceinline__ unsigned short f2bf(float f) {
    union { float f; uint32_t u; } v; v.f = f;
    uint32_t u = v.u;
    return (unsigned short)((u + 0x7FFFu + ((u >> 16) & 1u)) >> 16);
}
__device__ __forceinline__ uint32_t pack2(float a, float b) {
    uint32_t r;
    asm("v_cvt_pk_bf16_f32 %0, %1, %2" : "=v"(r) : "v"(a), "v"(b));
    return r;
}
__device__ __forceinline__ float bf2f(uint32_t lo16) { return __uint_as_float(lo16 << 16); }

__device__ __forceinline__ float fast_tanh(float x) {
    float cx = fminf(fmaxf(x, -10.f), 10.f);
    float e = __expf(2.f * cx);
    return (e - 1.f) * __builtin_amdgcn_rcpf(e + 1.f);
}
__device__ __forceinline__ float fast_sig(float z) {
    return __builtin_amdgcn_rcpf(1.f + __expf(-z));
}

// ---- prep (identical to r19) ----
__global__ void prep_kernel(const float* __restrict__ Wpre, const float* __restrict__ Wpost,
                            const float* __restrict__ Wres, const float* __restrict__ W1,
                            const float* __restrict__ W2, const float* __restrict__ ln_g,
                            const float* __restrict__ ln_b, const float* __restrict__ b1) {
    int b = blockIdx.x, t = threadIdx.x;
    if (b == 264) {
        int j = t;
        float sg = 0.f, sb = 0.f;
        const float* row = W1 + j * 128;
        #pragma unroll 4
        for (int c = 0; c < 128; c += 4) {
            float4 wv = *(const float4*)(row + c);
            float4 gv = *(const float4*)(ln_g + c);
            float4 bv = *(const float4*)(ln_b + c);
            sg += wv.x*gv.x + wv.y*gv.y + wv.z*gv.z + wv.w*gv.w;
            sb += wv.x*bv.x + wv.y*bv.y + wv.z*bv.z + wv.w*bv.w;
        }
        g_hA[j]   = b1[j] + sb;
        g_w1gs[j] = sg;
        return;
    }
    int idx = b * 512 + t;
    if (idx < 4096) {
        int e = idx & 7, lane = (idx >> 3) & 63, kk = (idx >> 9) & 3, tile = idx >> 11;
        int o = tile * 16 + (lane & 15);
        int c = kk * 32 + (lane >> 4) * 8 + e;
        float v = 0.f;
        if (o < 4)        v = Wpre[o*512+c] + Wpre[o*512+128+c] + Wpre[o*512+256+c] + Wpre[o*512+384+c];
        else if (o < 8)   { int j = o - 4;  v = Wpost[j*512+c] + Wpost[j*512+128+c] + Wpost[j*512+256+c] + Wpost[j*512+384+c]; }
        else if (o < 24)  { int j = o - 8;  v = Wres[j*512+c] + Wres[j*512+128+c] + Wres[j*512+256+c] + Wres[j*512+384+c]; }
        g_wefff[idx] = f2bf(v);
    } else if (idx < 69632) {
        int d = idx - 4096;
        int e = d & 7, lane = (d >> 3) & 63, kk = (d >> 9) & 3, jt = d >> 11;
        int j = jt * 16 + (lane & 15);
        int c = kk * 32 + (lane >> 4) * 8 + e;
        g_w1gf[d] = f2bf(W1[j * 128 + c] * ln_g[c]);
    } else if (idx < 135168) {
        int d = idx - 69632;   // 32x32x16 A-fragment layout for W2
        int e = d & 7, lane = (d >> 3) & 63, kk = (d >> 9) & 31, ct = (d >> 14) & 3;
        int c = ct * 32 + (lane & 31);
        int k = kk * 16 + (lane >> 5) * 8 + e;
        g_w2f[d] = f2bf(W2[c * 512 + k]);
    }
}

// ---- fused: coop p-load | B0 | route | B1 | Sinkhorn + GEMM1 + fold | B2 | GEMM2 | B3 | epilogue ----
__global__ void __launch_bounds__(512, 2) fused_kernel(
    const float* __restrict__ p, const float* __restrict__ p_mask,
    const float* __restrict__ b_pre, const float* __restrict__ b_post, const float* __restrict__ b_res,
    const float* __restrict__ a_pre, const float* __restrict__ a_post, const float* __restrict__ a_res,
    const float* __restrict__ b2g, float* __restrict__ out)
{
    __shared__ __align__(16) unsigned short pf_lds[8 * 64 * 8];   // 8 KB bf16 p fragments
    __shared__ __align__(16) unsigned short h32[32 * 64 * 8];     // 32 KB bf16 h, 32x32 B-fragment-linear
    __shared__ __align__(16) float redA[32 * RPAD];               // 16.9 KB D partial (k-half 0), [pix][c]
    __shared__ __align__(16) float redB[32 * RPAD];               // 16.9 KB D partial (k-half 1)
    __shared__ __align__(16) float A_s[128], B_s[128];
    __shared__ __align__(16) float2 simi_s[32];
    __shared__ __align__(16) float rms_s[32], mu_s[32], var_s[32];

    const int t = threadIdx.x;
    const int w = t >> 6, l = t & 63, lr = l & 15, lk = l >> 4;
    const size_t base = (size_t)blockIdx.x * TPIX;

    // ======== W1-fragment prefetch (kk=0,1) — issued before everything, consumed after B1 ========
    s16x8 aw01[8];
    #pragma unroll
    for (int kk = 0; kk < 2; ++kk)
        #pragma unroll
        for (int jt = 0; jt < 4; ++jt)
            aw01[kk * 4 + jt] = *(const s16x8*)(g_w1gf + ((size_t)((w * 4 + jt) * 4 + kk) * 64 + l) * 8);

    // ======== phase 0: cooperative p load + stats + pf fragments (all 512 threads) ========
    {
        int pix32 = t >> 4, ci = t & 15;
        const float* src = p + (base + pix32) * 128 + ci * 8;
        float4 va = *(const float4*)src;
        float4 vb = *(const float4*)(src + 4);
        float s  = va.x + va.y + va.z + va.w + vb.x + vb.y + vb.z + vb.w;
        float ss = va.x*va.x + va.y*va.y + va.z*va.z + va.w*va.w
                 + vb.x*vb.x + vb.y*vb.y + vb.z*vb.z + vb.w*vb.w;
        s += __shfl_xor(s, 1); ss += __shfl_xor(ss, 1);
        s += __shfl_xor(s, 2); ss += __shfl_xor(ss, 2);
        s += __shfl_xor(s, 4); ss += __shfl_xor(ss, 4);
        s += __shfl_xor(s, 8); ss += __shfl_xor(ss, 8);
        if (ci == 0) {
            float mu = s * (1.f / 128.f), mq = ss * (1.f / 128.f);
            rms_s[pix32] = rsqrtf(mq + 1.1920929e-07f);
            mu_s[pix32]  = mu;
            var_s[pix32] = mq - mu * mu;
        }
        uint4 u;
        u.x = pack2(va.x, va.y);
        u.y = pack2(va.z, va.w);
        u.z = pack2(vb.x, vb.y);
        u.w = pack2(vb.z, vb.w);
        uint32_t a16 = (uint32_t)((((pix32 >> 4) * 4 + (ci >> 2)) * 512
                     + ((pix32 & 15) + 16 * (ci & 3)) * 8));
        *(uint4*)(pf_lds + a16) = u;
    }
    __syncthreads();   // B0: pf + stats ready

    float M0 = 0.f, M1 = 0.f, M2 = 0.f, M3 = 0.f, sp = 0.f, hpm = 0.f;
    int mrow = 0, pix = 0;

    // ======== route (waves 0-1): MFMA from LDS pf, activations, M-init ========
    if (w < 2) {
        const int g = lk, pixl = lr;
        const size_t gpix = base + w * 16 + pixl;
        float apre = a_pre[0], apost = a_post[0], ares = a_res[0];
        float msk = p_mask[gpix];
        float bp0 = b_pre[0], bp1 = b_pre[1], bp2 = b_pre[2], bp3 = b_pre[3];
        float bq0 = b_post[0], bq1 = b_post[1], bq2 = b_post[2], bq3 = b_post[3];
        mrow = (g + 2) & 3;
        float br0 = b_res[mrow*4+0], br1 = b_res[mrow*4+1], br2 = b_res[mrow*4+2], br3 = b_res[mrow*4+3];

        float rv = rms_s[w * 16 + pixl];

        f32x4 y1 = {0.f, 0.f, 0.f, 0.f}, y2 = {0.f, 0.f, 0.f, 0.f};
        #pragma unroll
        for (int kk = 0; kk < 4; ++kk) {
            s16x8 bfr = *(const s16x8*)(pf_lds + (size_t)(w * 4 + kk) * 512 + l * 8);
            s16x8 a0 = *(const s16x8*)(g_wefff + ((size_t)(kk) * 64 + l) * 8);
            s16x8 a1 = *(const s16x8*)(g_wefff + ((size_t)(4 + kk) * 64 + l) * 8);
            y1 = MFMA16(a0, bfr, y1);
            y2 = MFMA16(a1, bfr, y2);
        }
        #pragma unroll
        for (int r = 0; r < 4; ++r) { y1[r] *= rv; y2[r] *= rv; }

        float sp_loc = fast_sig(apre * fast_tanh(y1[0]) + bp0)
                     + fast_sig(apre * fast_tanh(y1[1]) + bp1)
                     + fast_sig(apre * fast_tanh(y1[2]) + bp2)
                     + fast_sig(apre * fast_tanh(y1[3]) + bp3);
        sp = __shfl(sp_loc, pixl);

        float hp0 = 2.f * fast_sig(apost * fast_tanh(y1[0]) + bq0);
        float hp1 = 2.f * fast_sig(apost * fast_tanh(y1[1]) + bq1);
        float hp2 = 2.f * fast_sig(apost * fast_tanh(y1[2]) + bq2);
        float hp3 = 2.f * fast_sig(apost * fast_tanh(y1[3]) + bq3);

        bool lo = g < 2;
        M0 = __expf(ares * fast_tanh(lo ? y2[0] : y1[0]) + br0);
        M1 = __expf(ares * fast_tanh(lo ? y2[1] : y1[1]) + br1);
        M2 = __expf(ares * fast_tanh(lo ? y2[2] : y1[2]) + br2);
        M3 = __expf(ares * fast_tanh(lo ? y2[3] : y1[3]) + br3);

        float h0b = __shfl(hp0, pixl + 16);
        float h1b = __shfl(hp1, pixl + 16);
        float h2b = __shfl(hp2, pixl + 16);
        float h3b = __shfl(hp3, pixl + 16);
        hpm = (mrow & 2) ? ((mrow & 1) ? h3b : h2b) : ((mrow & 1) ? h1b : h0b);

        pix = w * 16 + pixl;
        B_s[pix * 4 + mrow] = hpm * msk;
        if (l < 16) {
            int px = w * 16 + lr;
            float istd = rsqrtf(sp * sp * var_s[px] + 1e-5f);
            simi_s[px] = make_float2(sp * istd, sp * mu_s[px] * istd);
        }
    }
    __syncthreads();   // B1: simi + B_s ready

    // ======== Sinkhorn on waves 0-1 (overlaps other waves' GEMM1) ========
    if (w < 2) {
        #pragma unroll 1
        for (int it = 0; it < 20; ++it) {
            float ri = __builtin_amdgcn_rcpf(M0 + M1 + M2 + M3);
            M0 *= ri; M1 *= ri; M2 *= ri; M3 *= ri;
            float c0 = M0, c1 = M1, c2 = M2, c3 = M3;
            c0 += __shfl_xor(c0, 16); c1 += __shfl_xor(c1, 16); c2 += __shfl_xor(c2, 16); c3 += __shfl_xor(c3, 16);
            c0 += __shfl_xor(c0, 32); c1 += __shfl_xor(c1, 32); c2 += __shfl_xor(c2, 32); c3 += __shfl_xor(c3, 32);
            M0 *= __builtin_amdgcn_rcpf(c0); M1 *= __builtin_amdgcn_rcpf(c1);
            M2 *= __builtin_amdgcn_rcpf(c2); M3 *= __builtin_amdgcn_rcpf(c3);
        }
        float rm = M0 + M1 + M2 + M3;
        A_s[pix * 4 + mrow] = rm + hpm * sp;
    }

    // ======== GEMM1 (single phase; kk=0,1 weights prefetched in registers) ========
    s16x8 pfr[2][4];
    #pragma unroll
    for (int it = 0; it < 2; ++it)
        #pragma unroll
        for (int kk = 0; kk < 4; ++kk)
            pfr[it][kk] = *(const s16x8*)(pf_lds + (size_t)(it * 4 + kk) * 512 + l * 8);

    f32x4 acc1[4][2] = {};
    #pragma unroll
    for (int kk = 0; kk < 2; ++kk)
        #pragma unroll
        for (int jt = 0; jt < 4; ++jt) {
            s16x8 a = aw01[kk * 4 + jt];
            acc1[jt][0] = MFMA16(a, pfr[0][kk], acc1[jt][0]);
            acc1[jt][1] = MFMA16(a, pfr[1][kk], acc1[jt][1]);
        }
    #pragma unroll
    for (int kk = 2; kk < 4; ++kk)
        #pragma unroll
        for (int jt = 0; jt < 4; ++jt) {
            s16x8 a = *(const s16x8*)(g_w1gf + ((size_t)((w * 4 + jt) * 4 + kk) * 64 + l) * 8);
            acc1[jt][0] = MFMA16(a, pfr[0][kk], acc1[jt][0]);
            acc1[jt][1] = MFMA16(a, pfr[1][kk], acc1[jt][1]);
        }

    // ======== fold -> h32 (32x32 B-fragment-linear layout) ========
    {
        float2 sim0 = simi_s[lr];
        float2 sim1 = simi_s[16 + lr];
        #pragma unroll
        for (int jt = 0; jt < 4; ++jt) {
            int j0 = w * 64 + jt * 16 + lk * 4;
            float4 wg = *(const float4*)(g_w1gs + j0);
            float4 ha = *(const float4*)(g_hA + j0);
            #pragma unroll
            for (int it = 0; it < 2; ++it) {
                float si = it ? sim1.x : sim0.x;
                float mi = it ? sim1.y : sim0.y;
                f32x4 v = acc1[jt][it];
                float h0 = fmaxf(fmaf(si, v[0], fmaf(-mi, wg.x, ha.x)), 0.f);
                float h1 = fmaxf(fmaf(si, v[1], fmaf(-mi, wg.y, ha.y)), 0.f);
                float h2 = fmaxf(fmaf(si, v[2], fmaf(-mi, wg.z, ha.z)), 0.f);
                float h3 = fmaxf(fmaf(si, v[3], fmaf(-mi, wg.w, ha.w)), 0.f);
                uint2 uu;
                uu.x = pack2(h0, h1);
                uu.y = pack2(h2, h3);
                uint32_t addr = (uint32_t)((w * 4 + jt) * 1024
                              + (it * 16 + lr + 32 * (lk >> 1)) * 16 + (lk & 1) * 8);
                *(uint2*)((char*)h32 + addr) = uu;
            }
        }
    }
    __syncthreads();   // B2: h32 ready

    // ======== GEMM2: 32x32x16, ct = w&3, k-half = w>>2 ; D partials -> redA/redB [pix][c] ========
    {
        const int ct = w & 3, kh = w >> 2;
        f32x16 acc2 = {0.f,0.f,0.f,0.f, 0.f,0.f,0.f,0.f, 0.f,0.f,0.f,0.f, 0.f,0.f,0.f,0.f};
        #pragma unroll 4
        for (int kk2 = 0; kk2 < 16; ++kk2) {
            int ks = kh * 16 + kk2;
            s16x8 a = *(const s16x8*)(g_w2f + ((size_t)(ct * 32 + ks) * 64 + l) * 8);
            s16x8 b = *(const s16x8*)(h32 + (size_t)ks * 512 + l * 8);
            acc2 = MFMA32(a, b, acc2);
        }
        float* red = kh ? redB : redA;
        int pixd = l & 31;
        #pragma unroll
        for (int q = 0; q < 4; ++q) {
            f32x4 v = {acc2[4*q+0], acc2[4*q+1], acc2[4*q+2], acc2[4*q+3]};
            int c = ct * 32 + 8 * q + 4 * (l >> 5);
            *(f32x4*)(red + pixd * RPAD + c) = v;
        }
    }
    __syncthreads();   // B3: D partials ready

    // ======== epilogue (all 8 waves, full-line stores) ========
    const int c0 = w * 16 + lk * 4;
    float4 b2v = *(const float4*)(b2g + c0);
    #pragma unroll
    for (int it = 0; it < 2; ++it) {
        int i = it * 16 + lr;
        f32x4 Av = *(const f32x4*)(A_s + i * 4);
        f32x4 Bv = *(const f32x4*)(B_s + i * 4);
        f32x4 Da = *(const f32x4*)(redA + i * RPAD + c0);
        f32x4 Db = *(const f32x4*)(redB + i * RPAD + c0);
        const unsigned short* pe = pf_lds
            + ((size_t)(it * 4 + (w >> 1)) * 64 + ((w & 1) * 2 + (lk >> 1)) * 16 + lr) * 8
            + (lk & 1) * 4;
        uint2 pb = *(const uint2*)pe;
        float p0 = bf2f(pb.x & 0xffffu), p1 = __uint_as_float(pb.x & 0xffff0000u);
        float p2 = bf2f(pb.y & 0xffffu), p3 = __uint_as_float(pb.y & 0xffff0000u);
        float d0 = Da[0] + Db[0] + b2v.x;
        float d1 = Da[1] + Db[1] + b2v.y;
        float d2 = Da[2] + Db[2] + b2v.z;
        float d3 = Da[3] + Db[3] + b2v.w;
        float* og = out + (base + i) * 512 + c0;
        #pragma unroll
        for (int m = 0; m < 4; ++m) {
            f32x4 o;
            o[0] = Av[m] * p0 + Bv[m] * d0;
            o[1] = Av[m] * p1 + Bv[m] * d1;
            o[2] = Av[m] * p2 + Bv[m] * d2;
            o[3] = Av[m] * p3 + Bv[m] * d3;
            *(f32x4*)(og + m * 128) = o;
        }
    }
}

extern "C" void kernel_launch(void* const* d_in, const int* in_sizes, int n_in,
                              void* d_out, int out_size, void* d_ws, size_t ws_size,
                              hipStream_t stream) {
    const float* p      = (const float*)d_in[0];
    const float* p_mask = (const float*)d_in[1];
    const float* W_pre  = (const float*)d_in[2];
    const float* W_post = (const float*)d_in[3];
    const float* W_res  = (const float*)d_in[4];
    const float* b_pre  = (const float*)d_in[5];
    const float* b_post = (const float*)d_in[6];
    const float* b_res  = (const float*)d_in[7];
    const float* a_pre  = (const float*)d_in[8];
    const float* a_post = (const float*)d_in[9];
    const float* a_res  = (const float*)d_in[10];
    const float* ln_g   = (const float*)d_in[11];
    const float* ln_b   = (const float*)d_in[12];
    const float* W1     = (const float*)d_in[13];
    const float* b1     = (const float*)d_in[14];
    const float* W2     = (const float*)d_in[15];
    const float* b2     = (const float*)d_in[16];
    float* out = (float*)d_out;

    prep_kernel<<<265, 512, 0, stream>>>(W_pre, W_post, W_res, W1, W2, ln_g, ln_b, b1);
    fused_kernel<<<2048, 512, 0, stream>>>(p, p_mask, b_pre, b_post, b_res,
                                           a_pre, a_post, a_res, b2, out);
}

// Round 21
// 69.995 us; speedup vs baseline: 1.8521x; 1.0154x over previous
//
#include <hip/hip_runtime.h>
#include <stdint.h>

// Problem constants (B=1, L=256, C=128, N=4, TN=4)
#define LLTOT 65536
#define CDIM  128
#define TPIX  32

typedef float f32x4  __attribute__((ext_vector_type(4)));
typedef short s16x8  __attribute__((ext_vector_type(8)));

#define MFMA16(a, b, c) __builtin_amdgcn_mfma_f32_16x16x32_bf16((a), (b), (c), 0, 0, 0)

// ---- persistent device scratch (weights only) ----
// g_wefff: routing weights 16x16 A-frags [tile2][kk4][lane][8]
// g_w1gf : W1*ln_g A-frags [T 0..31][kk4][lane][8]   j=T*16+(l&15), c=kk*32+(l>>4)*8+e
// g_w2f16: W2 A-frags      [ksg 0..15][ct 0..7][lane][8]  c=ct*16+(l&15), k=ksg*32+(l>>4)*8+e
__device__ __align__(16) unsigned short g_wefff[2 * 4 * 64 * 8];
__device__ __align__(16) unsigned short g_w1gf[32 * 4 * 64 * 8];
__device__ __align__(16) unsigned short g_w2f16[16 * 8 * 64 * 8];
__device__ __align__(16) float  g_hA[512];
__device__ __align__(16) float  g_w1gs[512];

__device__ __forceinline__ unsigned short f2bf(float f) {
    union { float f; uint32_t u; } v; v.f = f;
    uint32_t u = v.u;
    return (unsigned short)((u + 0x7FFFu + ((u >> 16) & 1u)) >> 16);
}
__device__ __forceinline__ uint32_t pack2(float a, float b) {
    uint32_t r;
    asm("v_cvt_pk_bf16_f32 %0, %1, %2" : "=v"(r) : "v"(a), "v"(b));
    return r;
}
__device__ __forceinline__ float bf2f(uint32_t lo16) { return __uint_as_float(lo16 << 16); }

__device__ __forceinline__ float fast_tanh(float x) {
    float cx = fminf(fmaxf(x, -10.f), 10.f);
    float e = __expf(2.f * cx);
    return (e - 1.f) * __builtin_amdgcn_rcpf(e + 1.f);
}
__device__ __forceinline__ float fast_sig(float z) {
    return __builtin_amdgcn_rcpf(1.f + __expf(-z));
}

// ---- prep ----
__global__ void prep_kernel(const float* __restrict__ Wpre, const float* __restrict__ Wpost,
                            const float* __restrict__ Wres, const float* __restrict__ W1,
                            const float* __restrict__ W2, const float* __restrict__ ln_g,
                            const float* __restrict__ ln_b, const float* __restrict__ b1) {
    int b = blockIdx.x, t = threadIdx.x;
    if (b == 264) {
        int j = t;
        float sg = 0.f, sb = 0.f;
        const float* row = W1 + j * 128;
        #pragma unroll 4
        for (int c = 0; c < 128; c += 4) {
            float4 wv = *(const float4*)(row + c);
            float4 gv = *(const float4*)(ln_g + c);
            float4 bv = *(const float4*)(ln_b + c);
            sg += wv.x*gv.x + wv.y*gv.y + wv.z*gv.z + wv.w*gv.w;
            sb += wv.x*bv.x + wv.y*bv.y + wv.z*bv.z + wv.w*bv.w;
        }
        g_hA[j]   = b1[j] + sb;
        g_w1gs[j] = sg;
        return;
    }
    int idx = b * 512 + t;
    if (idx < 4096) {
        int e = idx & 7, lane = (idx >> 3) & 63, kk = (idx >> 9) & 3, tile = idx >> 11;
        int o = tile * 16 + (lane & 15);
        int c = kk * 32 + (lane >> 4) * 8 + e;
        float v = 0.f;
        if (o < 4)        v = Wpre[o*512+c] + Wpre[o*512+128+c] + Wpre[o*512+256+c] + Wpre[o*512+384+c];
        else if (o < 8)   { int j = o - 4;  v = Wpost[j*512+c] + Wpost[j*512+128+c] + Wpost[j*512+256+c] + Wpost[j*512+384+c]; }
        else if (o < 24)  { int j = o - 8;  v = Wres[j*512+c] + Wres[j*512+128+c] + Wres[j*512+256+c] + Wres[j*512+384+c]; }
        g_wefff[idx] = f2bf(v);
    } else if (idx < 69632) {
        int d = idx - 4096;
        int e = d & 7, lane = (d >> 3) & 63, kk = (d >> 9) & 3, jt = d >> 11;
        int j = jt * 16 + (lane & 15);
        int c = kk * 32 + (lane >> 4) * 8 + e;
        g_w1gf[d] = f2bf(W1[j * 128 + c] * ln_g[c]);
    } else if (idx < 135168) {
        int d = idx - 69632;   // 16x16 A-frag layout for W2: [ksg][ct][lane][8]
        int e = d & 7, lane = (d >> 3) & 63, ct = (d >> 9) & 7, ksg = d >> 12;
        int c = ct * 16 + (lane & 15);
        int k = ksg * 32 + (lane >> 4) * 8 + e;
        g_w2f16[d] = f2bf(W2[c * 512 + k]);
    }
}

// ---- fused: coop p-load | B0 | route | B1 | Sinkhorn + GEMM1 + fold->h16 | B2 | GEMM2 + epilogue ----
__global__ void __launch_bounds__(512, 2) fused_kernel(
    const float* __restrict__ p, const float* __restrict__ p_mask,
    const float* __restrict__ b_pre, const float* __restrict__ b_post, const float* __restrict__ b_res,
    const float* __restrict__ a_pre, const float* __restrict__ a_post, const float* __restrict__ a_res,
    const float* __restrict__ b2g, float* __restrict__ out)
{
    __shared__ __align__(16) unsigned short pf_lds[8 * 512];      // 8 KB bf16 p fragments
    __shared__ __align__(16) unsigned short h16[32 * 512];        // 32 KB bf16 h, 16x16 B-frag-linear
    __shared__ __align__(16) float A_s[128], B_s[128];
    __shared__ __align__(16) float2 simi_s[32];
    __shared__ __align__(16) float rms_s[32], mu_s[32], var_s[32];

    const int t = threadIdx.x;
    const int w = t >> 6, l = t & 63, lr = l & 15, lk = l >> 4;
    const size_t base = (size_t)blockIdx.x * TPIX;

    // ======== W1-fragment prefetch (kk=0,1) — issued before everything, consumed after B1 ========
    s16x8 aw01[8];
    #pragma unroll
    for (int kk = 0; kk < 2; ++kk)
        #pragma unroll
        for (int jt = 0; jt < 4; ++jt)
            aw01[kk * 4 + jt] = *(const s16x8*)(g_w1gf + ((size_t)((w * 4 + jt) * 4 + kk) * 64 + l) * 8);

    // ======== phase 0: cooperative p load + stats + pf fragments (all 512 threads) ========
    {
        int pix32 = t >> 4, ci = t & 15;
        const float* src = p + (base + pix32) * 128 + ci * 8;
        float4 va = *(const float4*)src;
        float4 vb = *(const float4*)(src + 4);
        float s  = va.x + va.y + va.z + va.w + vb.x + vb.y + vb.z + vb.w;
        float ss = va.x*va.x + va.y*va.y + va.z*va.z + va.w*va.w
                 + vb.x*vb.x + vb.y*vb.y + vb.z*vb.z + vb.w*vb.w;
        s += __shfl_xor(s, 1); ss += __shfl_xor(ss, 1);
        s += __shfl_xor(s, 2); ss += __shfl_xor(ss, 2);
        s += __shfl_xor(s, 4); ss += __shfl_xor(ss, 4);
        s += __shfl_xor(s, 8); ss += __shfl_xor(ss, 8);
        if (ci == 0) {
            float mu = s * (1.f / 128.f), mq = ss * (1.f / 128.f);
            rms_s[pix32] = rsqrtf(mq + 1.1920929e-07f);
            mu_s[pix32]  = mu;
            var_s[pix32] = mq - mu * mu;
        }
        uint4 u;
        u.x = pack2(va.x, va.y);
        u.y = pack2(va.z, va.w);
        u.z = pack2(vb.x, vb.y);
        u.w = pack2(vb.z, vb.w);
        uint32_t a16 = (uint32_t)((((pix32 >> 4) * 4 + (ci >> 2)) * 512
                     + ((pix32 & 15) + 16 * (ci & 3)) * 8));
        *(uint4*)(pf_lds + a16) = u;
    }
    __syncthreads();   // B0: pf + stats ready

    float M0 = 0.f, M1 = 0.f, M2 = 0.f, M3 = 0.f, sp = 0.f, hpm = 0.f;
    int mrow = 0, pix = 0;

    // ======== route (waves 0-1): MFMA from LDS pf, activations, M-init ========
    if (w < 2) {
        const int g = lk, pixl = lr;
        const size_t gpix = base + w * 16 + pixl;
        float apre = a_pre[0], apost = a_post[0], ares = a_res[0];
        float msk = p_mask[gpix];
        float bp0 = b_pre[0], bp1 = b_pre[1], bp2 = b_pre[2], bp3 = b_pre[3];
        float bq0 = b_post[0], bq1 = b_post[1], bq2 = b_post[2], bq3 = b_post[3];
        mrow = (g + 2) & 3;
        float br0 = b_res[mrow*4+0], br1 = b_res[mrow*4+1], br2 = b_res[mrow*4+2], br3 = b_res[mrow*4+3];

        float rv = rms_s[w * 16 + pixl];

        f32x4 y1 = {0.f, 0.f, 0.f, 0.f}, y2 = {0.f, 0.f, 0.f, 0.f};
        #pragma unroll
        for (int kk = 0; kk < 4; ++kk) {
            s16x8 bfr = *(const s16x8*)(pf_lds + (size_t)(w * 4 + kk) * 512 + l * 8);
            s16x8 a0 = *(const s16x8*)(g_wefff + ((size_t)(kk) * 64 + l) * 8);
            s16x8 a1 = *(const s16x8*)(g_wefff + ((size_t)(4 + kk) * 64 + l) * 8);
            y1 = MFMA16(a0, bfr, y1);
            y2 = MFMA16(a1, bfr, y2);
        }
        #pragma unroll
        for (int r = 0; r < 4; ++r) { y1[r] *= rv; y2[r] *= rv; }

        float sp_loc = fast_sig(apre * fast_tanh(y1[0]) + bp0)
                     + fast_sig(apre * fast_tanh(y1[1]) + bp1)
                     + fast_sig(apre * fast_tanh(y1[2]) + bp2)
                     + fast_sig(apre * fast_tanh(y1[3]) + bp3);
        sp = __shfl(sp_loc, pixl);

        float hp0 = 2.f * fast_sig(apost * fast_tanh(y1[0]) + bq0);
        float hp1 = 2.f * fast_sig(apost * fast_tanh(y1[1]) + bq1);
        float hp2 = 2.f * fast_sig(apost * fast_tanh(y1[2]) + bq2);
        float hp3 = 2.f * fast_sig(apost * fast_tanh(y1[3]) + bq3);

        bool lo = g < 2;
        M0 = __expf(ares * fast_tanh(lo ? y2[0] : y1[0]) + br0);
        M1 = __expf(ares * fast_tanh(lo ? y2[1] : y1[1]) + br1);
        M2 = __expf(ares * fast_tanh(lo ? y2[2] : y1[2]) + br2);
        M3 = __expf(ares * fast_tanh(lo ? y2[3] : y1[3]) + br3);

        float h0b = __shfl(hp0, pixl + 16);
        float h1b = __shfl(hp1, pixl + 16);
        float h2b = __shfl(hp2, pixl + 16);
        float h3b = __shfl(hp3, pixl + 16);
        hpm = (mrow & 2) ? ((mrow & 1) ? h3b : h2b) : ((mrow & 1) ? h1b : h0b);

        pix = w * 16 + pixl;
        B_s[pix * 4 + mrow] = hpm * msk;
        if (l < 16) {
            int px = w * 16 + lr;
            float istd = rsqrtf(sp * sp * var_s[px] + 1e-5f);
            simi_s[px] = make_float2(sp * istd, sp * mu_s[px] * istd);
        }
    }
    __syncthreads();   // B1: simi + B_s ready

    // ======== Sinkhorn on waves 0-1 (overlaps other waves' GEMM1) ========
    if (w < 2) {
        #pragma unroll 1
        for (int it = 0; it < 20; ++it) {
            float ri = __builtin_amdgcn_rcpf(M0 + M1 + M2 + M3);
            M0 *= ri; M1 *= ri; M2 *= ri; M3 *= ri;
            float c0 = M0, c1 = M1, c2 = M2, c3 = M3;
            c0 += __shfl_xor(c0, 16); c1 += __shfl_xor(c1, 16); c2 += __shfl_xor(c2, 16); c3 += __shfl_xor(c3, 16);
            c0 += __shfl_xor(c0, 32); c1 += __shfl_xor(c1, 32); c2 += __shfl_xor(c2, 32); c3 += __shfl_xor(c3, 32);
            M0 *= __builtin_amdgcn_rcpf(c0); M1 *= __builtin_amdgcn_rcpf(c1);
            M2 *= __builtin_amdgcn_rcpf(c2); M3 *= __builtin_amdgcn_rcpf(c3);
        }
        float rm = M0 + M1 + M2 + M3;
        A_s[pix * 4 + mrow] = rm + hpm * sp;
    }

    // ======== GEMM1 (single phase; kk=0,1 weights prefetched in registers) ========
    s16x8 pfr[2][4];
    #pragma unroll
    for (int it = 0; it < 2; ++it)
        #pragma unroll
        for (int kk = 0; kk < 4; ++kk)
            pfr[it][kk] = *(const s16x8*)(pf_lds + (size_t)(it * 4 + kk) * 512 + l * 8);

    f32x4 acc1[4][2] = {};
    #pragma unroll
    for (int kk = 0; kk < 2; ++kk)
        #pragma unroll
        for (int jt = 0; jt < 4; ++jt) {
            s16x8 a = aw01[kk * 4 + jt];
            acc1[jt][0] = MFMA16(a, pfr[0][kk], acc1[jt][0]);
            acc1[jt][1] = MFMA16(a, pfr[1][kk], acc1[jt][1]);
        }
    #pragma unroll
    for (int kk = 2; kk < 4; ++kk)
        #pragma unroll
        for (int jt = 0; jt < 4; ++jt) {
            s16x8 a = *(const s16x8*)(g_w1gf + ((size_t)((w * 4 + jt) * 4 + kk) * 64 + l) * 8);
            acc1[jt][0] = MFMA16(a, pfr[0][kk], acc1[jt][0]);
            acc1[jt][1] = MFMA16(a, pfr[1][kk], acc1[jt][1]);
        }

    // ======== fold -> h16 (16x16 B-fragment-linear layout; conflict-free reads) ========
    {
        float2 sim0 = simi_s[lr];
        float2 sim1 = simi_s[16 + lr];
        #pragma unroll
        for (int jt = 0; jt < 4; ++jt) {
            int j0 = w * 64 + jt * 16 + lk * 4;
            float4 wg = *(const float4*)(g_w1gs + j0);
            float4 ha = *(const float4*)(g_hA + j0);
            int ksg = w * 2 + (jt >> 1);
            int laneB = lr + 16 * ((jt & 1) * 2 + (lk >> 1));
            #pragma unroll
            for (int it = 0; it < 2; ++it) {
                float si = it ? sim1.x : sim0.x;
                float mi = it ? sim1.y : sim0.y;
                f32x4 v = acc1[jt][it];
                float h0 = fmaxf(fmaf(si, v[0], fmaf(-mi, wg.x, ha.x)), 0.f);
                float h1 = fmaxf(fmaf(si, v[1], fmaf(-mi, wg.y, ha.y)), 0.f);
                float h2 = fmaxf(fmaf(si, v[2], fmaf(-mi, wg.z, ha.z)), 0.f);
                float h3 = fmaxf(fmaf(si, v[3], fmaf(-mi, wg.w, ha.w)), 0.f);
                uint2 uu;
                uu.x = pack2(h0, h1);
                uu.y = pack2(h2, h3);
                *(uint2*)(h16 + (size_t)(ksg * 2 + it) * 512 + laneB * 8 + (lk & 1) * 4) = uu;
            }
        }
    }
    __syncthreads();   // B2: h16 ready

    // ======== GEMM2: per-wave c-tile w, full K in-register (no partial-sum round-trip) ========
    f32x4 acc2[2] = {};
    #pragma unroll 4
    for (int ksg = 0; ksg < 16; ++ksg) {
        s16x8 a  = *(const s16x8*)(g_w2f16 + ((size_t)(ksg * 8 + w) * 64 + l) * 8);
        s16x8 b0 = *(const s16x8*)(h16 + (size_t)(ksg * 2 + 0) * 512 + l * 8);
        s16x8 b1 = *(const s16x8*)(h16 + (size_t)(ksg * 2 + 1) * 512 + l * 8);
        acc2[0] = MFMA16(a, b0, acc2[0]);
        acc2[1] = MFMA16(a, b1, acc2[1]);
    }

    // ======== epilogue (all 8 waves, full-line stores, D straight from registers) ========
    const int c0 = w * 16 + lk * 4;
    float4 b2v = *(const float4*)(b2g + c0);
    #pragma unroll
    for (int it = 0; it < 2; ++it) {
        int i = it * 16 + lr;
        f32x4 Av = *(const f32x4*)(A_s + i * 4);
        f32x4 Bv = *(const f32x4*)(B_s + i * 4);
        const unsigned short* pe = pf_lds
            + ((size_t)(it * 4 + (w >> 1)) * 64 + ((w & 1) * 2 + (lk >> 1)) * 16 + lr) * 8
            + (lk & 1) * 4;
        uint2 pb = *(const uint2*)pe;
        float p0 = bf2f(pb.x & 0xffffu), p1 = __uint_as_float(pb.x & 0xffff0000u);
        float p2 = bf2f(pb.y & 0xffffu), p3 = __uint_as_float(pb.y & 0xffff0000u);
        float d0 = acc2[it][0] + b2v.x, d1 = acc2[it][1] + b2v.y;
        float d2 = acc2[it][2] + b2v.z, d3 = acc2[it][3] + b2v.w;
        float* og = out + (base + i) * 512 + c0;
        #pragma unroll
        for (int m = 0; m < 4; ++m) {
            f32x4 o;
            o[0] = Av[m] * p0 + Bv[m] * d0;
            o[1] = Av[m] * p1 + Bv[m] * d1;
            o[2] = Av[m] * p2 + Bv[m] * d2;
            o[3] = Av[m] * p3 + Bv[m] * d3;
            *(f32x4*)(og + m * 128) = o;
        }
    }
}

extern "C" void kernel_launch(void* const* d_in, const int* in_sizes, int n_in,
                              void* d_out, int out_size, void* d_ws, size_t ws_size,
                              hipStream_t stream) {
    const float* p      = (const float*)d_in[0];
    const float* p_mask = (const float*)d_in[1];
    const float* W_pre  = (const float*)d_in[2];
    const float* W_post = (const float*)d_in[3];
    const float* W_res  = (const float*)d_in[4];
    const float* b_pre  = (const float*)d_in[5];
    const float* b_post = (const float*)d_in[6];
    const float* b_res  = (const float*)d_in[7];
    const float* a_pre  = (const float*)d_in[8];
    const float* a_post = (const float*)d_in[9];
    const float* a_res  = (const float*)d_in[10];
    const float* ln_g   = (const float*)d_in[11];
    const float* ln_b   = (const float*)d_in[12];
    const float* W1     = (const float*)d_in[13];
    const float* b1     = (const float*)d_in[14];
    const float* W2     = (const float*)d_in[15];
    const float* b2     = (const float*)d_in[16];
    float* out = (float*)d_out;

    prep_kernel<<<265, 512, 0, stream>>>(W_pre, W_post, W_res, W1, W2, ln_g, ln_b, b1);
    fused_kernel<<<2048, 512, 0, stream>>>(p, p_mask, b_pre, b_post, b_res,
                                           a_pre, a_post, a_res, b2, out);
}